// Round 16
// baseline (866.850 us; speedup 1.0000x reference)
//
#include <hip/hip_runtime.h>

typedef _Float16 f16;
typedef _Float16 f16x8 __attribute__((ext_vector_type(8)));
typedef float    f32x4 __attribute__((ext_vector_type(4)));
typedef unsigned int u32;
typedef u32 u32x4 __attribute__((ext_vector_type(4)));

#define MFMA16(a, b, c) __builtin_amdgcn_mfma_f32_16x16x32_f16((a), (b), (c), 0, 0, 0)

#define HSZ 262144            // 512*512
#define LOGDET_C 235.2482644923962f  // 128*log(2*pi)

// ---- memory access primitives (all proven r3-r15) -------------------------
__device__ __forceinline__ void ld16_s(u32x4& d, const f16* p) {
    asm volatile("global_load_dwordx4 %0, %1, off sc0 sc1" : "=v"(d) : "v"(p));
}
__device__ __forceinline__ void ldf_n(float& d, const float* p) {
    asm volatile("global_load_dword %0, %1, off" : "=v"(d) : "v"(p));
}
__device__ __forceinline__ void st2_s(f16* p, f16 v) {
    u32 u = (u32)__builtin_bit_cast(unsigned short, v);
    asm volatile("global_store_short %0, %1, off sc0 sc1" :: "v"(p), "v"(u) : "memory");
}
__device__ __forceinline__ void sti_s(int* p, int v) {
    asm volatile("global_store_dword %0, %1, off sc0 sc1" :: "v"(p), "v"(v) : "memory");
}
__device__ __forceinline__ int ldi_s(const int* p) {
    int v;
    asm volatile("global_load_dword %0, %1, off sc0 sc1\ns_waitcnt vmcnt(0)"
                 : "=v"(v) : "v"(p) : "memory");
    return v;
}
// async global->LDS 16B (per-lane global src, wave-linear LDS dest)
__device__ __forceinline__ void gl16(const f16* g, char* l) {
    __builtin_amdgcn_global_load_lds(
        (const __attribute__((address_space(1))) u32*)g,
        (__attribute__((address_space(3))) u32*)l, 16, 0, 0);
}
// tanh via HW exp2+rcp: tanh(x) = 1 - 2/(exp2(x*2/ln2)+1). |err| ~1e-6.
__device__ __forceinline__ float tanh_fast(float x) {
    float e = __builtin_amdgcn_exp2f(x * 2.8853900817779268f);
    return 1.f - 2.f * __builtin_amdgcn_rcpf(e + 1.f);
}

// ---------------------------------------------------------------------------
// k_conv: conversions + small vectors; init slots=0.
__global__ void k_conv(const float* __restrict__ x, const float* __restrict__ mask,
                       const float* __restrict__ Wih0,
                       const float* __restrict__ b_ih0, const float* __restrict__ b_hh0,
                       const float* __restrict__ Whh0, const float* __restrict__ Wih1,
                       const float* __restrict__ Whh1, const float* __restrict__ W1,
                       const float* __restrict__ W2,
                       f16* __restrict__ A, f16* __restrict__ B1,
                       float* __restrict__ biasv,
                       f16* __restrict__ Whh0h, f16* __restrict__ Wih1h,
                       f16* __restrict__ Whh1h, f16* __restrict__ W1h,
                       f16* __restrict__ W2h, f16* __restrict__ h1all,
                       int* __restrict__ slots)
{
    int gid = blockIdx.x * 256 + threadIdx.x;   // 0..65535
    {
        int c = gid >> 7, k = gid & 127;
        A[gid]  = (f16)(x[gid] * mask[k]);
        B1[gid] = (f16)Wih0[c * 257 + 1 + k];
    }
    if (gid < 512) {
        float s = b_ih0[gid] + b_hh0[gid];
        const float* wrow = Wih0 + gid * 257 + 129;
        for (int k = 0; k < 128; k++) s += mask[k] * wrow[k];
        biasv[gid] = s;
    }
    for (int i = gid; i < 262144; i += 65536) {
        Whh0h[i] = (f16)Whh0[i];
        Wih1h[i] = (f16)Wih1[i];
        Whh1h[i] = (f16)Whh1[i];
        h1all[i] = (f16)0.f;      // h1[t=-1]
    }
    for (int i = gid; i < 1048576; i += 65536) W1h[i] = (f16)W1[i];
    for (int i = gid; i < 524288;  i += 65536) W2h[i] = (f16)W2[i];
    if (gid < 32768) slots[gid] = 0;
}

// ---------------------------------------------------------------------------
// k_base: base = A @ B1^T + biasv ; h0 slab0 = tanh(base)
__global__ __launch_bounds__(256) void k_base(const f16* __restrict__ A,
                                              const f16* __restrict__ B1,
                                              const float* __restrict__ biasv,
                                              float* __restrict__ base,
                                              f16* __restrict__ h0s0)
{
    __shared__ float part[4][32][32];
    int tid = threadIdx.x;
    int w = tid >> 6, l = tid & 63;
    int R0 = (blockIdx.x >> 4) * 32, C0 = (blockIdx.x & 15) * 32;
    int lr = l & 15, hi = l >> 4;

    const f16* a0p = A  + (R0 + lr) * 128 + w * 32 + hi * 8;
    const f16* b0p = B1 + (C0 + lr) * 128 + w * 32 + hi * 8;
    f16x8 a0 = *(const f16x8*)(a0p);
    f16x8 a1 = *(const f16x8*)(a0p + 16 * 128);
    f16x8 b0 = *(const f16x8*)(b0p);
    f16x8 b1 = *(const f16x8*)(b0p + 16 * 128);
    f32x4 z = {0.f, 0.f, 0.f, 0.f};
    f32x4 acc00 = MFMA16(a0, b0, z);
    f32x4 acc01 = MFMA16(a0, b1, z);
    f32x4 acc10 = MFMA16(a1, b0, z);
    f32x4 acc11 = MFMA16(a1, b1, z);
#pragma unroll
    for (int r = 0; r < 4; r++) {
        part[w][hi * 4 + r][lr]           = acc00[r];
        part[w][hi * 4 + r][16 + lr]      = acc01[r];
        part[w][16 + hi * 4 + r][lr]      = acc10[r];
        part[w][16 + hi * 4 + r][16 + lr] = acc11[r];
    }
    __syncthreads();
    int rr = tid >> 3, c0 = (tid & 7) * 4;
    int gr = R0 + rr;
#pragma unroll
    for (int cc = 0; cc < 4; cc++) {
        int gc = C0 + c0 + cc;
        float s = part[0][rr][c0 + cc] + part[1][rr][c0 + cc] +
                  part[2][rr][c0 + cc] + part[3][rr][c0 + cc] + biasv[gc];
        base[gr * 512 + gc] = s;
        h0s0[gr * 512 + gc] = (f16)tanh_fast(s);
    }
}

// ---------------------------------------------------------------------------
// Persistent recurrence kernel v12: WAVE-ROLE SPECIALIZATION.
//   waves 0-1: h0 pipeline (the serial recurrence): pollB -> stage h0[p] ->
//     M2 (Whh0 in VGPR) -> tanh/store h0[p+1] -> sigB. Critical cycle only.
//   waves 2-3: h1 pipeline: M1 (Wih1 from LDS x h0[p]) -> pollA -> stage
//     h1[p-1] -> M3 (Whh1) -> tanh/store h1[p] -> sigA. Runs in parallel on
//     separate SIMDs; off the critical path.
//   Coupling via single-writer LDS flags (uniform-exit polls, init -1):
//     stg0[2]@0  : h0 wave w staged its 16 rows of h0[p]
//     m1d [2]@8  : h1 wave finished M1 reads of h0 buf (phase p)
//     stg1[2]@16 : h1 wave staged its 16 rows of h1[p-1]
//     m3d [2]@24 : h1 wave finished M3 reads of h1 buf
//     m2d [2]@32 : h0 wave finished M2 reads of h0 buf
//   Buffer-reuse: stage h0(p) waits m1d>=p-1 & m2d[partner]>=p-1;
//                 stage h1(p) waits m3d[partner]>=p-1.  All <=p references,
//   unconditional posts -> deadlock-free by induction (base p=0 uses init).
//   Memory semantics byte-identical to r11 (proven): st2_s write-through,
//   plain gl16 loads on virgin monotonic slabs, sc0sc1 global flag slots.
#define LDH2(off, rbase, f) (*(const f16x8*)((char*)Wl + (off) + (rbase) + \
        ((((f) * 64 + hi16)) ^ lswz)))
#define LDB(m, f) (*(const f16x8*)((char*)Wl + \
        ((((m) * 32768 + colL * 1024 + (f) * 64 + hi16)) ^ cswz)))

// Fallback (2-slab h0 ring, small ws): r11's proven direct-load path.
#define RNN_DIRECT()                                                          \
    for (int p = 0; p < 128; p++) {                                           \
        const f16* H0 = h0all + (size_t)(p & 1) * HSZ;                        \
        const f16* H1 = h1all + (size_t)p * HSZ;                              \
        const f16* ap = H0 + (R0 + r_lo + lr) * 512 + hi * 8;                 \
        const f16* bp = H1 + (R0 + r_lo + lr) * 512 + hi * 8;                 \
        f16* H1o = h1all + (size_t)(p + 1) * HSZ;                             \
        f16* H0o = h0all + (size_t)((p + 1) & 1) * HSZ;                       \
        float xprev[4];                                                       \
        _Pragma("unroll")                                                     \
        for (int r = 0; r < 4; r++) ldf_n(xprev[r], x + (outrow + r) * 128 + p); \
        if (p) { int v; for (;;) { v = ldi_s(pollBd); if (__all(v >= p)) break; \
                                   __builtin_amdgcn_s_sleep(1); } }           \
        u32x4 ra0[16], ra1[16];                                               \
        __builtin_amdgcn_sched_barrier(0);                                    \
        _Pragma("unroll")                                                     \
        for (int f = 0; f < 16; f++) ld16_s(ra0[f], ap + f * 32);             \
        asm volatile("s_waitcnt vmcnt(0)" ::: "memory");                      \
        __builtin_amdgcn_sched_barrier(0);                                    \
        f32x4 z4 = {0.f, 0.f, 0.f, 0.f};                                      \
        f32x4 a0a = z4, a0b = z4, a1a = z4, a1b = z4;                         \
        _Pragma("unroll")                                                     \
        for (int f = 0; f < 16; f += 2) {                                     \
            f16x8 A0 = __builtin_bit_cast(f16x8, ra0[f]);                     \
            f16x8 A1 = __builtin_bit_cast(f16x8, ra0[f + 1]);                 \
            a0a = MFMA16(A0, bW0[f],     a0a);                                \
            a0b = MFMA16(A1, bW0[f + 1], a0b);                                \
            a1a = MFMA16(A0, LDB(0, f),     a1a);                             \
            a1b = MFMA16(A1, LDB(0, f + 1), a1b);                             \
        }                                                                     \
        f32x4 acc0 = a0a + a0b;                                               \
        _Pragma("unroll")                                                     \
        for (int r = 0; r < 4; r++) {                                         \
            f16 v0 = (f16)tanh_fast(acc0[r] + basef[r] + xprev[r] * w0);      \
            st2_s(H0o + (outrow + r) * 512 + outcolg, v0);                    \
        }                                                                     \
        asm volatile("s_waitcnt vmcnt(0)" ::: "memory");                      \
        if (l == 0) sti_s(myBd, p + 1);                                       \
        if (p) { int v; for (;;) { v = ldi_s(pollAd); if (__all(v >= p)) break; \
                                   __builtin_amdgcn_s_sleep(1); } }           \
        __builtin_amdgcn_sched_barrier(0);                                    \
        _Pragma("unroll")                                                     \
        for (int f = 0; f < 16; f++) ld16_s(ra1[f], bp + f * 32);             \
        asm volatile("s_waitcnt vmcnt(0)" ::: "memory");                      \
        __builtin_amdgcn_sched_barrier(0);                                    \
        _Pragma("unroll")                                                     \
        for (int f = 0; f < 16; f += 2) {                                     \
            a1a = MFMA16(__builtin_bit_cast(f16x8, ra1[f]),     LDB(1, f),     a1a); \
            a1b = MFMA16(__builtin_bit_cast(f16x8, ra1[f + 1]), LDB(1, f + 1), a1b); \
        }                                                                     \
        f32x4 acc1 = a1a + a1b;                                               \
        _Pragma("unroll")                                                     \
        for (int r = 0; r < 4; r++) {                                         \
            f16 v1 = (f16)tanh_fast(acc1[r] + bsum);                          \
            st2_s(H1o + (outrow + r) * 512 + outcolg, v1);                    \
        }                                                                     \
        asm volatile("s_waitcnt vmcnt(0)" ::: "memory");                      \
        if (l == 0) sti_s(myAd, p + 1);                                       \
    }

template<bool H0F>
__global__ __launch_bounds__(256, 1) void k_rnn(
    f16* __restrict__ h0all, f16* __restrict__ h1all,
    const f16* __restrict__ Whh0h, const f16* __restrict__ Wih1h,
    const f16* __restrict__ Whh1h,
    const float* __restrict__ base, const float* __restrict__ x,
    const float* __restrict__ Wih0, const float* __restrict__ b_ih1,
    const float* __restrict__ b_hh1, int* __restrict__ slots)
{
    const int OFF_H0S = 65536, OFF_H1S = 98304;
    __shared__ __align__(16) char Wl[131072];  // 64K weights + 32K h0s + 32K h1s
    __shared__ int flg[64];
    volatile int* vflg = flg;
    int tid = threadIdx.x;
    int w = tid >> 6, l = tid & 63;
    int bid = blockIdx.x;
    int cluster = (bid & 7) * 2 + ((bid >> 3) & 1);   // cluster-mates share bid&7
    int cj = bid >> 4;
    int R0 = cluster * 32, C0 = cj * 32;

    if (tid < 64) flg[tid] = -1;

    // ---- stage Wih1/Whh1 col-slices into LDS with chunk-XOR swizzle (r11)
    {
        const f16* srcs[2] = { Wih1h, Whh1h };
        for (int m = 0; m < 2; m++) {
            const f16* S = srcs[m] + (size_t)C0 * 512;
            for (int cch = tid; cch < 2048; cch += 256) {
                int col = cch >> 6, kc = cch & 63;
                f16x8 v = *(const f16x8*)(S + col * 512 + kc * 8);
                int byte = m * 32768 + col * 1024 + kc * 16;
                byte ^= (col & 7) << 4;
                *(f16x8*)((char*)Wl + byte) = v;
            }
        }
    }
    __syncthreads();

    int lr = l & 15, hi = l >> 4;
    int hi16 = hi * 16;
    int lswz = (lr & 7) << 4;
    int rbA = lr * 1024, rbB = (16 + lr) * 1024;   // A-frag row bases

    if constexpr (!H0F) {
        // ------- fallback: r11 4-wave direct path -------
        int r_lo = (w >> 1) * 16, c_lo = (w & 1) * 16;
        int outrow = R0 + r_lo + hi * 4;
        int outcolg = C0 + c_lo + lr;
        int colL = c_lo + lr;
        int cswz = (colL & 7) << 4;
        f16x8 bW0[16];
        {
            const f16* w0p = Whh0h + (size_t)outcolg * 512 + hi * 8;
#pragma unroll
            for (int f = 0; f < 16; f++) bW0[f] = *(const f16x8*)(w0p + f * 32);
        }
        float basef[4];
#pragma unroll
        for (int r = 0; r < 4; r++) basef[r] = base[(outrow + r) * 512 + outcolg];
        float w0 = Wih0[outcolg * 257];
        float bsum = b_ih1[outcolg] + b_hh1[outcolg];
        int* slotA = slots;
        int* slotB = slots + 16384;
        int* myAd = slotA + (cluster * 64 + cj * 4 + w) * 16;
        int* myBd = slotB + (cluster * 64 + cj * 4 + w) * 16;
        const int* pollAd = slotA + (cluster * 64 + l) * 16;
        const int* pollBd = slotB + (cluster * 64 + l) * 16;
        RNN_DIRECT()
        return;
    } else {
    // ------- wave-role-specialized path -------
    int* slotA = slots;
    int* slotB = slots + 16384;

    if (w < 2) {
        // ======== h0 producer pipeline (waves 0,1) ========
        int outcol = C0 + w * 16 + lr;
        int colL_unused = 0; (void)colL_unused;
        f16x8 bW0[16];
        {
            const f16* w0p = Whh0h + (size_t)outcol * 512 + hi * 8;
#pragma unroll
            for (int f = 0; f < 16; f++) bW0[f] = *(const f16x8*)(w0p + f * 32);
        }
        float basef[8];
#pragma unroll
        for (int g = 0; g < 2; g++)
#pragma unroll
            for (int r = 0; r < 4; r++)
                basef[g * 4 + r] = base[(R0 + g * 16 + hi * 4 + r) * 512 + outcol];
        float w0 = Wih0[outcol * 257];
        int* myB = slotB + (cluster * 32 + cj * 2 + w) * 16;
        const int* pollB = slotB + (cluster * 32 + (l & 31)) * 16;

        for (int p = 0; p < 128; p++) {
            const f16* H0 = h0all + (size_t)p * HSZ;
            f16* H0o = h0all + (size_t)(p + 1) * HSZ;
            float xp[8];
#pragma unroll
            for (int g = 0; g < 2; g++)
#pragma unroll
                for (int r = 0; r < 4; r++)
                    ldf_n(xp[g * 4 + r], x + (R0 + g * 16 + hi * 4 + r) * 128 + p);
            if (p) {
                int v;
                for (;;) { v = ldi_s(pollB); if (__all(v >= p)) break;
                           __builtin_amdgcn_s_sleep(1); }
            }
            // buffer free: h1 M1 reads + partner M2 reads of phase p-1 done
            while (vflg[8] < p - 1 || vflg[9] < p - 1 || vflg[32 + (w ^ 1)] < p - 1)
                __builtin_amdgcn_s_sleep(1);
#pragma unroll
            for (int i = 0; i < 16; i++) {
                int rr = w * 16 + i;
                gl16(H0 + (size_t)(R0 + rr) * 512 + ((l ^ (rr & 7)) * 8),
                     (char*)Wl + OFF_H0S + rr * 1024);
            }
            asm volatile("s_waitcnt vmcnt(0)" ::: "memory");
            if (l == 0) vflg[w] = p;
            while (vflg[w ^ 1] < p) __builtin_amdgcn_s_sleep(1);
            __builtin_amdgcn_sched_barrier(0);
            f32x4 z4 = {0.f, 0.f, 0.f, 0.f};
            f32x4 aca = z4, acb = z4;
#pragma unroll
            for (int f = 0; f < 16; f++) {
                aca = MFMA16(LDH2(OFF_H0S, rbA, f), bW0[f], aca);
                acb = MFMA16(LDH2(OFF_H0S, rbB, f), bW0[f], acb);
            }
            asm volatile("s_waitcnt lgkmcnt(0)" ::: "memory");
            __builtin_amdgcn_sched_barrier(0);
            if (l == 0) vflg[32 + w] = p;          // M2 reads done
#pragma unroll
            for (int r = 0; r < 4; r++) {
                st2_s(H0o + (R0 + hi * 4 + r) * 512 + outcol,
                      (f16)tanh_fast(aca[r] + basef[r] + xp[r] * w0));
                st2_s(H0o + (R0 + 16 + hi * 4 + r) * 512 + outcol,
                      (f16)tanh_fast(acb[r] + basef[4 + r] + xp[4 + r] * w0));
            }
            asm volatile("s_waitcnt vmcnt(0)" ::: "memory");
            if (l == 0) sti_s(myB, p + 1);
        }
    } else {
        // ======== h1 pipeline (waves 2,3) ========
        int sub = w - 2;
        int outcol = C0 + sub * 16 + lr;
        int colL = sub * 16 + lr;
        int cswz = (colL & 7) << 4;
        float bsum = b_ih1[outcol] + b_hh1[outcol];
        int* myA = slotA + (cluster * 32 + cj * 2 + sub) * 16;
        const int* pollA = slotA + (cluster * 32 + (l & 31)) * 16;

        for (int p = 0; p < 128; p++) {
            const f16* H1 = h1all + (size_t)p * HSZ;       // h1[p-1]
            f16* H1o = h1all + (size_t)(p + 1) * HSZ;      // h1[p]
            // wait h0[p] staged by both h0 waves
            while (vflg[0] < p || vflg[1] < p) __builtin_amdgcn_s_sleep(1);
            __builtin_amdgcn_sched_barrier(0);
            f32x4 z4 = {0.f, 0.f, 0.f, 0.f};
            f32x4 aca = z4, acb = z4;
#pragma unroll
            for (int f = 0; f < 16; f++) {
                aca = MFMA16(LDH2(OFF_H0S, rbA, f), LDB(0, f), aca);
                acb = MFMA16(LDH2(OFF_H0S, rbB, f), LDB(0, f), acb);
            }
            asm volatile("s_waitcnt lgkmcnt(0)" ::: "memory");
            __builtin_amdgcn_sched_barrier(0);
            if (l == 0) vflg[8 + sub] = p;         // M1 reads done
            if (p) {
                int v;
                for (;;) { v = ldi_s(pollA); if (__all(v >= p)) break;
                           __builtin_amdgcn_s_sleep(1); }
            }
            // h1 buf free: partner's M3 reads of phase p-1 done
            while (vflg[24 + (sub ^ 1)] < p - 1) __builtin_amdgcn_s_sleep(1);
#pragma unroll
            for (int i = 0; i < 16; i++) {
                int rr = sub * 16 + i;
                gl16(H1 + (size_t)(R0 + rr) * 512 + ((l ^ (rr & 7)) * 8),
                     (char*)Wl + OFF_H1S + rr * 1024);
            }
            asm volatile("s_waitcnt vmcnt(0)" ::: "memory");
            if (l == 0) vflg[16 + sub] = p;
            while (vflg[16 + (sub ^ 1)] < p) __builtin_amdgcn_s_sleep(1);
            __builtin_amdgcn_sched_barrier(0);
#pragma unroll
            for (int f = 0; f < 16; f++) {
                aca = MFMA16(LDH2(OFF_H1S, rbA, f), LDB(1, f), aca);
                acb = MFMA16(LDH2(OFF_H1S, rbB, f), LDB(1, f), acb);
            }
            asm volatile("s_waitcnt lgkmcnt(0)" ::: "memory");
            __builtin_amdgcn_sched_barrier(0);
            if (l == 0) vflg[24 + sub] = p;        // M3 reads done
#pragma unroll
            for (int r = 0; r < 4; r++) {
                st2_s(H1o + (R0 + hi * 4 + r) * 512 + outcol,
                      (f16)tanh_fast(aca[r] + bsum));
                st2_s(H1o + (R0 + 16 + hi * 4 + r) * 512 + outcol,
                      (f16)tanh_fast(acb[r] + bsum));
            }
            asm volatile("s_waitcnt vmcnt(0)" ::: "memory");
            if (l == 0) sti_s(myA, p + 1);
        }
    }
    }
}
#undef LDH2
#undef LDB

// ---------------------------------------------------------------------------
// Phase B v3 (unchanged from round 5)
__global__ __launch_bounds__(512, 2) void k_phaseB(const f16* __restrict__ h1all,
                                                   const f16* __restrict__ W1h,
                                                   const f16* __restrict__ W2h,
                                                   const float* __restrict__ b1v,
                                                   const float* __restrict__ b2,
                                                   const float* __restrict__ x,
                                                   float* __restrict__ pcontrib)
{
    __shared__ __align__(16) char Wl[108544];
    const int OFF_W2 = 65536, OFF_HID = 98304;

    int tid = threadIdx.x;
    int wv = tid >> 6, l = tid & 63;
    int lr = l & 15, hi = l >> 4;
    int M0 = blockIdx.x * 128;

    const f16* Hrow = h1all + HSZ + (size_t)(M0 + wv * 16 + lr) * 512;
    f16x8 afrag[16];
#pragma unroll
    for (int ks = 0; ks < 16; ks++)
        afrag[ks] = *(const f16x8*)(Hrow + ks * 32 + hi * 8);

    f32x4 mc[16] = {};

    {
#pragma unroll
        for (int it = 0; it < 4; it++) {
            int idx = it * 512 + tid;
            gl16(W1h + (size_t)(idx & 31) * 512 + (idx >> 5) * 8,
                 Wl + idx * 16);
        }
#pragma unroll
        for (int it = 0; it < 2; it++) {
            int idx = it * 512 + tid;
            gl16(W2h + (size_t)(idx & 255) * 2048 + (idx >> 8) * 8,
                 Wl + OFF_W2 + idx * 16);
        }
    }

    for (int c = 0; c < 64; c++) {
        int p = c & 1;
        __syncthreads();

        if (c + 1 < 64) {
            const int nc = (c + 1) * 32, q = p ^ 1;
#pragma unroll
            for (int it = 0; it < 4; it++) {
                int idx = it * 512 + tid;
                gl16(W1h + (size_t)(nc + (idx & 31)) * 512 + (idx >> 5) * 8,
                     Wl + q * 32768 + idx * 16);
            }
#pragma unroll
            for (int it = 0; it < 2; it++) {
                int idx = it * 512 + tid;
                gl16(W2h + (size_t)(idx & 255) * 2048 + nc + (idx >> 8) * 8,
                     Wl + OFF_W2 + q * 16384 + idx * 16);
            }
        }

        {
            f32x4 s3a = {0.f, 0.f, 0.f, 0.f}, s3b = s3a;
#pragma unroll
            for (int ks = 0; ks < 16; ks++) {
                f16x8 wb0 = *(const f16x8*)(Wl + p * 32768 +
                                            ((ks * 4 + hi) * 32 + lr) * 16);
                f16x8 wb1 = *(const f16x8*)(Wl + p * 32768 +
                                            ((ks * 4 + hi) * 32 + 16 + lr) * 16);
                s3a = MFMA16(afrag[ks], wb0, s3a);
                s3b = MFMA16(afrag[ks], wb1, s3b);
            }
            float bb0 = b1v[c * 32 + lr];
            float bb1 = b1v[c * 32 + 16 + lr];
#pragma unroll
            for (int r = 0; r < 4; r++) {
                int lrow = wv * 16 + hi * 4 + r;
                *(f16*)(Wl + OFF_HID + (lrow * 40 + lr) * 2) =
                    (f16)fmaxf(s3a[r] + bb0, 0.f);
                *(f16*)(Wl + OFF_HID + (lrow * 40 + 16 + lr) * 2) =
                    (f16)fmaxf(s3b[r] + bb1, 0.f);
            }
        }
        __syncthreads();

        {
            f16x8 a = *(const f16x8*)(Wl + OFF_HID +
                                      ((wv * 16 + lr) * 40 + hi * 8) * 2);
#pragma unroll
            for (int cf = 0; cf < 16; cf++) {
                f16x8 b = *(const f16x8*)(Wl + OFF_W2 + p * 16384 +
                                          (hi * 256 + cf * 16 + lr) * 16);
                mc[cf] = MFMA16(a, b, mc[cf]);
            }
        }
    }

    float quad[4] = {}, ls[4] = {}, xt[4];
#pragma unroll
    for (int r = 0; r < 4; r++) {
        int m = M0 + wv * 16 + hi * 4 + r;
        xt[r] = x[(m & 511) * 128 + (m >> 9)];
    }
#pragma unroll
    for (int cf = 0; cf < 8; cf++) {
        int cc = cf * 16 + lr;
        float bm = b2[cc], bc = b2[128 + cc];
#pragma unroll
        for (int r = 0; r < 4; r++) {
            float mean = mc[cf][r] + bm;
            float cov  = mc[cf + 8][r] + bc;
            float sp = log1pf(expf(-fabsf(cov))) + fmaxf(cov, 0.f);
            float d = xt[r] - mean;
            quad[r] += d * d * sp;
            ls[r] += logf(sp);
        }
    }
#pragma unroll
    for (int mm = 1; mm < 16; mm <<= 1)
#pragma unroll
        for (int r = 0; r < 4; r++) {
            quad[r] += __shfl_xor(quad[r], mm, 64);
            ls[r]   += __shfl_xor(ls[r], mm, 64);
        }
    if (lr == 0) {
#pragma unroll
        for (int r = 0; r < 4; r++) {
            int m = M0 + wv * 16 + hi * 4 + r;
            pcontrib[m] = -0.5f * (LOGDET_C + quad[r]) - 0.5f * ls[r];
        }
    }
}

// ---------------------------------------------------------------------------
__global__ void k_fin(const f16* __restrict__ h1last,
                      const float* __restrict__ pcontrib, float* __restrict__ out)
{
    int gid = blockIdx.x * 256 + threadIdx.x;
    for (int i = gid; i < HSZ; i += 131072) out[i] = (float)h1last[i];
    if (gid < 512) {
        float s = 0.f;
        for (int tt = 0; tt < 128; tt++) s += pcontrib[tt * 512 + gid];
        out[HSZ + gid] = s;
    }
}

// ---------------------------------------------------------------------------
extern "C" void kernel_launch(void* const* d_in, const int* in_sizes, int n_in,
                              void* d_out, int out_size, void* d_ws, size_t ws_size,
                              hipStream_t stream) {
    const float* x     = (const float*)d_in[0];
    const float* mask  = (const float*)d_in[1];
    const float* Wih0  = (const float*)d_in[2];
    const float* Whh0  = (const float*)d_in[3];
    const float* b_ih0 = (const float*)d_in[4];
    const float* b_hh0 = (const float*)d_in[5];
    const float* Wih1  = (const float*)d_in[6];
    const float* Whh1  = (const float*)d_in[7];
    const float* b_ih1 = (const float*)d_in[8];
    const float* b_hh1 = (const float*)d_in[9];
    const float* W1    = (const float*)d_in[10];
    const float* b1    = (const float*)d_in[11];
    const float* W2    = (const float*)d_in[12];
    const float* b2    = (const float*)d_in[13];

    char* ws = (char*)d_ws;
    size_t off = 0;
    auto take = [&](size_t bytes) { char* p = ws + off; off += (bytes + 255) & ~(size_t)255; return p; };
    float* base    = (float*)take(512 * 512 * 4);
    f16* Whh0h     = (f16*)take(HSZ * 2);
    f16* Wih1h     = (f16*)take(HSZ * 2);
    f16* Whh1h     = (f16*)take(HSZ * 2);
    f16* W1h       = (f16*)take(1048576 * 2);
    f16* W2h       = (f16*)take(524288 * 2);
    f16* h0buf     = (f16*)take(2 * HSZ * 2);
    f16* h1all     = (f16*)take((size_t)129 * HSZ * 2);
    float* pcontrib= (float*)take(128 * 512 * 4);
    f16* A         = (f16*)take(65536 * 2);
    f16* B1        = (f16*)take(65536 * 2);
    float* biasv   = (float*)take(512 * 4);
    int* slots     = (int*)take(32768 * 4);
    if (off > ws_size) return;

    // Optional monotonic h0 slabs (66 MB): enables cached/virgin h0 reads
    // and the wave-specialized fast kernel.
    const size_t h0all_bytes = (size_t)129 * HSZ * 2;
    bool big = (off + h0all_bytes + 256 <= ws_size);
    f16* h0all = big ? (f16*)take(h0all_bytes) : h0buf;

    k_conv<<<256, 256, 0, stream>>>(x, mask, Wih0, b_ih0, b_hh0, Whh0, Wih1, Whh1,
                                    W1, W2, A, B1, biasv, Whh0h, Wih1h, Whh1h,
                                    W1h, W2h, h1all, slots);
    k_base<<<256, 256, 0, stream>>>(A, B1, biasv, base, h0all);
    if (big)
        k_rnn<true><<<256, 256, 0, stream>>>(h0all, h1all, Whh0h, Wih1h, Whh1h,
                                             base, x, Wih0, b_ih1, b_hh1, slots);
    else
        k_rnn<false><<<256, 256, 0, stream>>>(h0all, h1all, Whh0h, Wih1h, Whh1h,
                                              base, x, Wih0, b_ih1, b_hh1, slots);
    k_phaseB<<<512, 512, 0, stream>>>(h1all, W1h, W2h, b1, b2, x, pcontrib);
    k_fin<<<512, 256, 0, stream>>>(h1all + (size_t)128 * HSZ, pcontrib, (float*)d_out);
}

// Round 17
// 850.167 us; speedup vs baseline: 1.0196x; 1.0196x over previous
//
#include <hip/hip_runtime.h>

typedef _Float16 f16;
typedef _Float16 f16x8 __attribute__((ext_vector_type(8)));
typedef float    f32x4 __attribute__((ext_vector_type(4)));
typedef unsigned int u32;
typedef u32 u32x4 __attribute__((ext_vector_type(4)));

#define MFMA16(a, b, c) __builtin_amdgcn_mfma_f32_16x16x32_f16((a), (b), (c), 0, 0, 0)

#define HSZ 262144            // 512*512
#define LOGDET_C 235.2482644923962f  // 128*log(2*pi)

// ---- memory access primitives (all proven r3-r15) -------------------------
__device__ __forceinline__ void ld16_s(u32x4& d, const f16* p) {
    asm volatile("global_load_dwordx4 %0, %1, off sc0 sc1" : "=v"(d) : "v"(p));
}
__device__ __forceinline__ void ldf_n(float& d, const float* p) {
    asm volatile("global_load_dword %0, %1, off" : "=v"(d) : "v"(p));
}
__device__ __forceinline__ void st2_s(f16* p, f16 v) {
    u32 u = (u32)__builtin_bit_cast(unsigned short, v);
    asm volatile("global_store_short %0, %1, off sc0 sc1" :: "v"(p), "v"(u) : "memory");
}
__device__ __forceinline__ void sti_s(int* p, int v) {
    asm volatile("global_store_dword %0, %1, off sc0 sc1" :: "v"(p), "v"(v) : "memory");
}
__device__ __forceinline__ int ldi_s(const int* p) {
    int v;
    asm volatile("global_load_dword %0, %1, off sc0 sc1\ns_waitcnt vmcnt(0)"
                 : "=v"(v) : "v"(p) : "memory");
    return v;
}
// async global->LDS 16B (per-lane global src, wave-linear LDS dest)
__device__ __forceinline__ void gl16(const f16* g, char* l) {
    __builtin_amdgcn_global_load_lds(
        (const __attribute__((address_space(1))) u32*)g,
        (__attribute__((address_space(3))) u32*)l, 16, 0, 0);
}
// tanh via HW exp2+rcp: tanh(x) = 1 - 2/(exp2(x*2/ln2)+1). |err| ~1e-6.
__device__ __forceinline__ float tanh_fast(float x) {
    float e = __builtin_amdgcn_exp2f(x * 2.8853900817779268f);
    return 1.f - 2.f * __builtin_amdgcn_rcpf(e + 1.f);
}

// ---------------------------------------------------------------------------
// k_conv: conversions + small vectors; init slots=0.
__global__ void k_conv(const float* __restrict__ x, const float* __restrict__ mask,
                       const float* __restrict__ Wih0,
                       const float* __restrict__ b_ih0, const float* __restrict__ b_hh0,
                       const float* __restrict__ Whh0, const float* __restrict__ Wih1,
                       const float* __restrict__ Whh1, const float* __restrict__ W1,
                       const float* __restrict__ W2,
                       f16* __restrict__ A, f16* __restrict__ B1,
                       float* __restrict__ biasv,
                       f16* __restrict__ Whh0h, f16* __restrict__ Wih1h,
                       f16* __restrict__ Whh1h, f16* __restrict__ W1h,
                       f16* __restrict__ W2h, f16* __restrict__ h1all,
                       int* __restrict__ slots)
{
    int gid = blockIdx.x * 256 + threadIdx.x;   // 0..65535
    {
        int c = gid >> 7, k = gid & 127;
        A[gid]  = (f16)(x[gid] * mask[k]);
        B1[gid] = (f16)Wih0[c * 257 + 1 + k];
    }
    if (gid < 512) {
        float s = b_ih0[gid] + b_hh0[gid];
        const float* wrow = Wih0 + gid * 257 + 129;
        for (int k = 0; k < 128; k++) s += mask[k] * wrow[k];
        biasv[gid] = s;
    }
    for (int i = gid; i < 262144; i += 65536) {
        Whh0h[i] = (f16)Whh0[i];
        Wih1h[i] = (f16)Wih1[i];
        Whh1h[i] = (f16)Whh1[i];
        h1all[i] = (f16)0.f;      // h1[t=-1]
    }
    for (int i = gid; i < 1048576; i += 65536) W1h[i] = (f16)W1[i];
    for (int i = gid; i < 524288;  i += 65536) W2h[i] = (f16)W2[i];
    if (gid < 32768) slots[gid] = 0;
}

// ---------------------------------------------------------------------------
// k_base: base = A @ B1^T + biasv ; h0 slab0 = tanh(base)
__global__ __launch_bounds__(256) void k_base(const f16* __restrict__ A,
                                              const f16* __restrict__ B1,
                                              const float* __restrict__ biasv,
                                              float* __restrict__ base,
                                              f16* __restrict__ h0s0)
{
    __shared__ float part[4][32][32];
    int tid = threadIdx.x;
    int w = tid >> 6, l = tid & 63;
    int R0 = (blockIdx.x >> 4) * 32, C0 = (blockIdx.x & 15) * 32;
    int lr = l & 15, hi = l >> 4;

    const f16* a0p = A  + (R0 + lr) * 128 + w * 32 + hi * 8;
    const f16* b0p = B1 + (C0 + lr) * 128 + w * 32 + hi * 8;
    f16x8 a0 = *(const f16x8*)(a0p);
    f16x8 a1 = *(const f16x8*)(a0p + 16 * 128);
    f16x8 b0 = *(const f16x8*)(b0p);
    f16x8 b1 = *(const f16x8*)(b0p + 16 * 128);
    f32x4 z = {0.f, 0.f, 0.f, 0.f};
    f32x4 acc00 = MFMA16(a0, b0, z);
    f32x4 acc01 = MFMA16(a0, b1, z);
    f32x4 acc10 = MFMA16(a1, b0, z);
    f32x4 acc11 = MFMA16(a1, b1, z);
#pragma unroll
    for (int r = 0; r < 4; r++) {
        part[w][hi * 4 + r][lr]           = acc00[r];
        part[w][hi * 4 + r][16 + lr]      = acc01[r];
        part[w][16 + hi * 4 + r][lr]      = acc10[r];
        part[w][16 + hi * 4 + r][16 + lr] = acc11[r];
    }
    __syncthreads();
    int rr = tid >> 3, c0 = (tid & 7) * 4;
    int gr = R0 + rr;
#pragma unroll
    for (int cc = 0; cc < 4; cc++) {
        int gc = C0 + c0 + cc;
        float s = part[0][rr][c0 + cc] + part[1][rr][c0 + cc] +
                  part[2][rr][c0 + cc] + part[3][rr][c0 + cc] + biasv[gc];
        base[gr * 512 + gc] = s;
        h0s0[gr * 512 + gc] = (f16)tanh_fast(s);
    }
}

// ---------------------------------------------------------------------------
// Persistent recurrence kernel: EXACT r11 structure (proven 450 us), with the
// never-engaged xcdtab verification removed. Contiguous-row gl16 staging with
// chunk-XOR swizzle, pollB-first, early sigB, per-wave sc0sc1 slots.
#define LDH(off, f) (*(const f16x8*)((char*)Wl + (off) + lrowB + \
        ((((f) * 64 + hi16)) ^ lswz)))
#define LDB(m, f) (*(const f16x8*)((char*)Wl + \
        ((((m) * 32768 + colL * 1024 + (f) * 64 + hi16)) ^ cswz)))

#define RNN_STAGED()                                                          \
    for (int p = 0; p < 128; p++) {                                           \
        const f16* H0 = h0all + (size_t)p * HSZ;                              \
        const f16* H1 = h1all + (size_t)p * HSZ;                              \
        f16* H1o = h1all + (size_t)(p + 1) * HSZ;                             \
        f16* H0o = h0all + (size_t)(p + 1) * HSZ;                             \
        float xprev[4];                                                       \
        _Pragma("unroll")                                                     \
        for (int r = 0; r < 4; r++) ldf_n(xprev[r], x + (outrow + r) * 128 + p); \
        if (p) { int v; for (;;) { v = ldi_s(pollB); if (__all(v >= p)) break; \
                                   __builtin_amdgcn_s_sleep(1); } }           \
        _Pragma("unroll")                                                     \
        for (int i = 0; i < 8; i++) {                                         \
            int rr = w * 8 + i;                                               \
            gl16(H0 + (size_t)(R0 + rr) * 512 + ((l ^ (rr & 7)) * 8),         \
                 (char*)Wl + OFF_H0S + rr * 1024);                            \
        }                                                                     \
        asm volatile("s_waitcnt vmcnt(0)" ::: "memory");                      \
        __syncthreads();                                                      \
        f32x4 z4 = {0.f, 0.f, 0.f, 0.f};                                      \
        f32x4 a0a = z4, a0b = z4, a1a = z4, a1b = z4;                         \
        _Pragma("unroll")                                                     \
        for (int f = 0; f < 16; f += 2) {                                     \
            f16x8 A0 = LDH(OFF_H0S, f);                                       \
            f16x8 A1 = LDH(OFF_H0S, f + 1);                                   \
            a0a = MFMA16(A0, bW0[f],     a0a);                                \
            a0b = MFMA16(A1, bW0[f + 1], a0b);                                \
            a1a = MFMA16(A0, LDB(0, f),     a1a);                             \
            a1b = MFMA16(A1, LDB(0, f + 1), a1b);                             \
        }                                                                     \
        f32x4 acc0 = a0a + a0b;                                               \
        _Pragma("unroll")                                                     \
        for (int r = 0; r < 4; r++) {                                         \
            f16 v0 = (f16)tanh_fast(acc0[r] + basef[r] + xprev[r] * w0);      \
            st2_s(H0o + (outrow + r) * 512 + outcolg, v0);                    \
        }                                                                     \
        asm volatile("s_waitcnt vmcnt(0)" ::: "memory");                      \
        if (l == 0) sti_s(myB, p + 1);                                        \
        if (p) { int v; for (;;) { v = ldi_s(pollA); if (__all(v >= p)) break; \
                                   __builtin_amdgcn_s_sleep(1); } }           \
        _Pragma("unroll")                                                     \
        for (int i = 0; i < 8; i++) {                                         \
            int rr = w * 8 + i;                                               \
            gl16(H1 + (size_t)(R0 + rr) * 512 + ((l ^ (rr & 7)) * 8),         \
                 (char*)Wl + OFF_H1S + rr * 1024);                            \
        }                                                                     \
        asm volatile("s_waitcnt vmcnt(0)" ::: "memory");                      \
        __syncthreads();                                                      \
        _Pragma("unroll")                                                     \
        for (int f = 0; f < 16; f += 2) {                                     \
            a1a = MFMA16(LDH(OFF_H1S, f),     LDB(1, f),     a1a);            \
            a1b = MFMA16(LDH(OFF_H1S, f + 1), LDB(1, f + 1), a1b);            \
        }                                                                     \
        f32x4 acc1 = a1a + a1b;                                               \
        _Pragma("unroll")                                                     \
        for (int r = 0; r < 4; r++) {                                         \
            f16 v1 = (f16)tanh_fast(acc1[r] + bsum);                          \
            st2_s(H1o + (outrow + r) * 512 + outcolg, v1);                    \
        }                                                                     \
        asm volatile("s_waitcnt vmcnt(0)" ::: "memory");                      \
        if (l == 0) sti_s(myA, p + 1);                                        \
    }

// Fallback (2-slab h0 ring, small ws): r11's proven direct-load path.
#define RNN_DIRECT()                                                          \
    for (int p = 0; p < 128; p++) {                                           \
        const f16* H0 = h0all + (size_t)(p & 1) * HSZ;                        \
        const f16* H1 = h1all + (size_t)p * HSZ;                              \
        const f16* ap = H0 + (R0 + r_lo + lr) * 512 + hi * 8;                 \
        const f16* bp = H1 + (R0 + r_lo + lr) * 512 + hi * 8;                 \
        f16* H1o = h1all + (size_t)(p + 1) * HSZ;                             \
        f16* H0o = h0all + (size_t)((p + 1) & 1) * HSZ;                       \
        float xprev[4];                                                       \
        _Pragma("unroll")                                                     \
        for (int r = 0; r < 4; r++) ldf_n(xprev[r], x + (outrow + r) * 128 + p); \
        if (p) { int v; for (;;) { v = ldi_s(pollB); if (__all(v >= p)) break; \
                                   __builtin_amdgcn_s_sleep(1); } }           \
        u32x4 ra0[16], ra1[16];                                               \
        __builtin_amdgcn_sched_barrier(0);                                    \
        _Pragma("unroll")                                                     \
        for (int f = 0; f < 16; f++) ld16_s(ra0[f], ap + f * 32);             \
        asm volatile("s_waitcnt vmcnt(0)" ::: "memory");                      \
        __builtin_amdgcn_sched_barrier(0);                                    \
        f32x4 z4 = {0.f, 0.f, 0.f, 0.f};                                      \
        f32x4 a0a = z4, a0b = z4, a1a = z4, a1b = z4;                         \
        _Pragma("unroll")                                                     \
        for (int f = 0; f < 16; f += 2) {                                     \
            f16x8 A0 = __builtin_bit_cast(f16x8, ra0[f]);                     \
            f16x8 A1 = __builtin_bit_cast(f16x8, ra0[f + 1]);                 \
            a0a = MFMA16(A0, bW0[f],     a0a);                                \
            a0b = MFMA16(A1, bW0[f + 1], a0b);                                \
            a1a = MFMA16(A0, LDB(0, f),     a1a);                             \
            a1b = MFMA16(A1, LDB(0, f + 1), a1b);                             \
        }                                                                     \
        f32x4 acc0 = a0a + a0b;                                               \
        _Pragma("unroll")                                                     \
        for (int r = 0; r < 4; r++) {                                         \
            f16 v0 = (f16)tanh_fast(acc0[r] + basef[r] + xprev[r] * w0);      \
            st2_s(H0o + (outrow + r) * 512 + outcolg, v0);                    \
        }                                                                     \
        asm volatile("s_waitcnt vmcnt(0)" ::: "memory");                      \
        if (l == 0) sti_s(myB, p + 1);                                        \
        if (p) { int v; for (;;) { v = ldi_s(pollA); if (__all(v >= p)) break; \
                                   __builtin_amdgcn_s_sleep(1); } }           \
        __builtin_amdgcn_sched_barrier(0);                                    \
        _Pragma("unroll")                                                     \
        for (int f = 0; f < 16; f++) ld16_s(ra1[f], bp + f * 32);             \
        asm volatile("s_waitcnt vmcnt(0)" ::: "memory");                      \
        __builtin_amdgcn_sched_barrier(0);                                    \
        _Pragma("unroll")                                                     \
        for (int f = 0; f < 16; f += 2) {                                     \
            a1a = MFMA16(__builtin_bit_cast(f16x8, ra1[f]),     LDB(1, f),     a1a); \
            a1b = MFMA16(__builtin_bit_cast(f16x8, ra1[f + 1]), LDB(1, f + 1), a1b); \
        }                                                                     \
        f32x4 acc1 = a1a + a1b;                                               \
        _Pragma("unroll")                                                     \
        for (int r = 0; r < 4; r++) {                                         \
            f16 v1 = (f16)tanh_fast(acc1[r] + bsum);                          \
            st2_s(H1o + (outrow + r) * 512 + outcolg, v1);                    \
        }                                                                     \
        asm volatile("s_waitcnt vmcnt(0)" ::: "memory");                      \
        if (l == 0) sti_s(myA, p + 1);                                        \
    }

template<bool H0F>
__global__ __launch_bounds__(256, 1) void k_rnn(
    f16* __restrict__ h0all, f16* __restrict__ h1all,
    const f16* __restrict__ Whh0h, const f16* __restrict__ Wih1h,
    const f16* __restrict__ Whh1h,
    const float* __restrict__ base, const float* __restrict__ x,
    const float* __restrict__ Wih0, const float* __restrict__ b_ih1,
    const float* __restrict__ b_hh1, int* __restrict__ slots)
{
    const int OFF_H0S = 65536, OFF_H1S = 98304;
    __shared__ __align__(16) char Wl[131072];  // 64K weights + 32K h0s + 32K h1s
    int tid = threadIdx.x;
    int w = tid >> 6, l = tid & 63;
    int bid = blockIdx.x;
    int cluster = (bid & 7) * 2 + ((bid >> 3) & 1);   // cluster-mates share bid&7
    int cj = bid >> 4;
    int R0 = cluster * 32, C0 = cj * 32;

    // ---- stage Wih1/Whh1 col-slices into LDS with chunk-XOR swizzle
    {
        const f16* srcs[2] = { Wih1h, Whh1h };
        for (int m = 0; m < 2; m++) {
            const f16* S = srcs[m] + (size_t)C0 * 512;
            for (int cch = tid; cch < 2048; cch += 256) {
                int col = cch >> 6, kc = cch & 63;
                f16x8 v = *(const f16x8*)(S + col * 512 + kc * 8);
                int byte = m * 32768 + col * 1024 + kc * 16;
                byte ^= (col & 7) << 4;
                *(f16x8*)((char*)Wl + byte) = v;
            }
        }
    }
    __syncthreads();

    int lr = l & 15, hi = l >> 4;
    int r_lo = (w >> 1) * 16, c_lo = (w & 1) * 16;
    int outrow = R0 + r_lo + hi * 4;
    int outcolg = C0 + c_lo + lr;
    int colL = c_lo + lr;
    int lrow = r_lo + lr;
    int lrowB = lrow * 1024;
    int hi16 = hi * 16;
    int lswz = (lrow & 7) << 4;
    int cswz = (colL & 7) << 4;

    // ---- Whh0 B-fragments in registers (64 VGPR)
    f16x8 bW0[16];
    {
        const f16* w0p = Whh0h + (size_t)outcolg * 512 + hi * 8;
#pragma unroll
        for (int f = 0; f < 16; f++) bW0[f] = *(const f16x8*)(w0p + f * 32);
    }

    float basef[4];
#pragma unroll
    for (int r = 0; r < 4; r++) basef[r] = base[(outrow + r) * 512 + outcolg];
    float w0 = Wih0[outcolg * 257];
    float bsum = b_ih1[outcolg] + b_hh1[outcolg];

    // ---- per-wave slots (A = slots[0..16K), B = slots[16K..32K))
    int* slotA = slots;
    int* slotB = slots + 16384;
    int wslot = cj * 4 + w;
    int* myA = slotA + (cluster * 64 + wslot) * 16;
    int* myB = slotB + (cluster * 64 + wslot) * 16;
    const int* pollA = slotA + (cluster * 64 + l) * 16;
    const int* pollB = slotB + (cluster * 64 + l) * 16;

    if constexpr (H0F) {
        RNN_STAGED()           // monotonic slabs: staged plain reads, L3 stores
    } else {
        RNN_DIRECT()           // 2-slab ring: full L3 coherence
    }
}
#undef LDH
#undef LDB

// ---------------------------------------------------------------------------
// Phase B v4: identical to v3 except the next-chunk staging is issued AFTER
// the "hid complete" barrier (was: before S3). m97 lesson: __syncthreads
// drains vmcnt to 0, so issuing staging before barrier #2 stalled every chunk
// on the fresh 48KB queue. Now S4 + the next top-of-loop barrier cover it.
__global__ __launch_bounds__(512, 2) void k_phaseB(const f16* __restrict__ h1all,
                                                   const f16* __restrict__ W1h,
                                                   const f16* __restrict__ W2h,
                                                   const float* __restrict__ b1v,
                                                   const float* __restrict__ b2,
                                                   const float* __restrict__ x,
                                                   float* __restrict__ pcontrib)
{
    __shared__ __align__(16) char Wl[108544];
    const int OFF_W2 = 65536, OFF_HID = 98304;

    int tid = threadIdx.x;
    int wv = tid >> 6, l = tid & 63;
    int lr = l & 15, hi = l >> 4;
    int M0 = blockIdx.x * 128;

    const f16* Hrow = h1all + HSZ + (size_t)(M0 + wv * 16 + lr) * 512;
    f16x8 afrag[16];
#pragma unroll
    for (int ks = 0; ks < 16; ks++)
        afrag[ks] = *(const f16x8*)(Hrow + ks * 32 + hi * 8);

    f32x4 mc[16] = {};

    // prologue: stage chunk 0 into buf 0
    {
#pragma unroll
        for (int it = 0; it < 4; it++) {
            int idx = it * 512 + tid;
            gl16(W1h + (size_t)(idx & 31) * 512 + (idx >> 5) * 8,
                 Wl + idx * 16);
        }
#pragma unroll
        for (int it = 0; it < 2; it++) {
            int idx = it * 512 + tid;
            gl16(W2h + (size_t)(idx & 255) * 2048 + (idx >> 8) * 8,
                 Wl + OFF_W2 + idx * 16);
        }
    }

    for (int c = 0; c < 64; c++) {
        int p = c & 1;
        __syncthreads();   // staged buf p ready (per-wave vmcnt drain)

        // ---- S3: hid[128][32] = relu(H_tile @ W1c^T + b1)
        {
            f32x4 s3a = {0.f, 0.f, 0.f, 0.f}, s3b = s3a;
#pragma unroll
            for (int ks = 0; ks < 16; ks++) {
                f16x8 wb0 = *(const f16x8*)(Wl + p * 32768 +
                                            ((ks * 4 + hi) * 32 + lr) * 16);
                f16x8 wb1 = *(const f16x8*)(Wl + p * 32768 +
                                            ((ks * 4 + hi) * 32 + 16 + lr) * 16);
                s3a = MFMA16(afrag[ks], wb0, s3a);
                s3b = MFMA16(afrag[ks], wb1, s3b);
            }
            float bb0 = b1v[c * 32 + lr];
            float bb1 = b1v[c * 32 + 16 + lr];
#pragma unroll
            for (int r = 0; r < 4; r++) {
                int lrow = wv * 16 + hi * 4 + r;
                *(f16*)(Wl + OFF_HID + (lrow * 40 + lr) * 2) =
                    (f16)fmaxf(s3a[r] + bb0, 0.f);
                *(f16*)(Wl + OFF_HID + (lrow * 40 + 16 + lr) * 2) =
                    (f16)fmaxf(s3b[r] + bb1, 0.f);
            }
        }
        __syncthreads();   // hid complete (no staging in flight -> no stall)

        if (c + 1 < 64) {  // stage next chunk AFTER barrier; S4 covers latency
            const int nc = (c + 1) * 32, q = p ^ 1;
#pragma unroll
            for (int it = 0; it < 4; it++) {
                int idx = it * 512 + tid;
                gl16(W1h + (size_t)(nc + (idx & 31)) * 512 + (idx >> 5) * 8,
                     Wl + q * 32768 + idx * 16);
            }
#pragma unroll
            for (int it = 0; it < 2; it++) {
                int idx = it * 512 + tid;
                gl16(W2h + (size_t)(idx & 255) * 2048 + nc + (idx >> 8) * 8,
                     Wl + OFF_W2 + q * 16384 + idx * 16);
            }
        }

        // ---- S4: mc[16 rows][256] += hid(own rows) @ W2c^T
        {
            f16x8 a = *(const f16x8*)(Wl + OFF_HID +
                                      ((wv * 16 + lr) * 40 + hi * 8) * 2);
#pragma unroll
            for (int cf = 0; cf < 16; cf++) {
                f16x8 b = *(const f16x8*)(Wl + OFF_W2 + p * 16384 +
                                          (hi * 256 + cf * 16 + lr) * 16);
                mc[cf] = MFMA16(a, b, mc[cf]);
            }
        }
    }

    // ---- epilogue: GMM log-prob
    float quad[4] = {}, ls[4] = {}, xt[4];
#pragma unroll
    for (int r = 0; r < 4; r++) {
        int m = M0 + wv * 16 + hi * 4 + r;
        xt[r] = x[(m & 511) * 128 + (m >> 9)];
    }
#pragma unroll
    for (int cf = 0; cf < 8; cf++) {
        int cc = cf * 16 + lr;
        float bm = b2[cc], bc = b2[128 + cc];
#pragma unroll
        for (int r = 0; r < 4; r++) {
            float mean = mc[cf][r] + bm;
            float cov  = mc[cf + 8][r] + bc;
            float sp = log1pf(expf(-fabsf(cov))) + fmaxf(cov, 0.f);
            float d = xt[r] - mean;
            quad[r] += d * d * sp;
            ls[r] += logf(sp);
        }
    }
#pragma unroll
    for (int mm = 1; mm < 16; mm <<= 1)
#pragma unroll
        for (int r = 0; r < 4; r++) {
            quad[r] += __shfl_xor(quad[r], mm, 64);
            ls[r]   += __shfl_xor(ls[r], mm, 64);
        }
    if (lr == 0) {
#pragma unroll
        for (int r = 0; r < 4; r++) {
            int m = M0 + wv * 16 + hi * 4 + r;
            pcontrib[m] = -0.5f * (LOGDET_C + quad[r]) - 0.5f * ls[r];
        }
    }
}

// ---------------------------------------------------------------------------
__global__ void k_fin(const f16* __restrict__ h1last,
                      const float* __restrict__ pcontrib, float* __restrict__ out)
{
    int gid = blockIdx.x * 256 + threadIdx.x;
    for (int i = gid; i < HSZ; i += 131072) out[i] = (float)h1last[i];
    if (gid < 512) {
        float s = 0.f;
        for (int tt = 0; tt < 128; tt++) s += pcontrib[tt * 512 + gid];
        out[HSZ + gid] = s;
    }
}

// ---------------------------------------------------------------------------
extern "C" void kernel_launch(void* const* d_in, const int* in_sizes, int n_in,
                              void* d_out, int out_size, void* d_ws, size_t ws_size,
                              hipStream_t stream) {
    const float* x     = (const float*)d_in[0];
    const float* mask  = (const float*)d_in[1];
    const float* Wih0  = (const float*)d_in[2];
    const float* Whh0  = (const float*)d_in[3];
    const float* b_ih0 = (const float*)d_in[4];
    const float* b_hh0 = (const float*)d_in[5];
    const float* Wih1  = (const float*)d_in[6];
    const float* Whh1  = (const float*)d_in[7];
    const float* b_ih1 = (const float*)d_in[8];
    const float* b_hh1 = (const float*)d_in[9];
    const float* W1    = (const float*)d_in[10];
    const float* b1    = (const float*)d_in[11];
    const float* W2    = (const float*)d_in[12];
    const float* b2    = (const float*)d_in[13];

    char* ws = (char*)d_ws;
    size_t off = 0;
    auto take = [&](size_t bytes) { char* p = ws + off; off += (bytes + 255) & ~(size_t)255; return p; };
    float* base    = (float*)take(512 * 512 * 4);
    f16* Whh0h     = (f16*)take(HSZ * 2);
    f16* Wih1h     = (f16*)take(HSZ * 2);
    f16* Whh1h     = (f16*)take(HSZ * 2);
    f16* W1h       = (f16*)take(1048576 * 2);
    f16* W2h       = (f16*)take(524288 * 2);
    f16* h0buf     = (f16*)take(2 * HSZ * 2);
    f16* h1all     = (f16*)take((size_t)129 * HSZ * 2);
    float* pcontrib= (float*)take(128 * 512 * 4);
    f16* A         = (f16*)take(65536 * 2);
    f16* B1        = (f16*)take(65536 * 2);
    float* biasv   = (float*)take(512 * 4);
    int* slots     = (int*)take(32768 * 4);
    if (off > ws_size) return;

    // Optional monotonic h0 slabs (66 MB): enables cached/virgin h0 reads.
    const size_t h0all_bytes = (size_t)129 * HSZ * 2;
    bool big = (off + h0all_bytes + 256 <= ws_size);
    f16* h0all = big ? (f16*)take(h0all_bytes) : h0buf;

    k_conv<<<256, 256, 0, stream>>>(x, mask, Wih0, b_ih0, b_hh0, Whh0, Wih1, Whh1,
                                    W1, W2, A, B1, biasv, Whh0h, Wih1h, Whh1h,
                                    W1h, W2h, h1all, slots);
    k_base<<<256, 256, 0, stream>>>(A, B1, biasv, base, h0all);
    if (big)
        k_rnn<true><<<256, 256, 0, stream>>>(h0all, h1all, Whh0h, Wih1h, Whh1h,
                                             base, x, Wih0, b_ih1, b_hh1, slots);
    else
        k_rnn<false><<<256, 256, 0, stream>>>(h0all, h1all, Whh0h, Wih1h, Whh1h,
                                              base, x, Wih0, b_ih1, b_hh1, slots);
    k_phaseB<<<512, 512, 0, stream>>>(h1all, W1h, W2h, b1, b2, x, pcontrib);
    k_fin<<<512, 256, 0, stream>>>(h1all + (size_t)128 * HSZ, pcontrib, (float*)d_out);
}

// Round 18
// 834.098 us; speedup vs baseline: 1.0393x; 1.0193x over previous
//
#include <hip/hip_runtime.h>

typedef _Float16 f16;
typedef _Float16 f16x8 __attribute__((ext_vector_type(8)));
typedef float    f32x4 __attribute__((ext_vector_type(4)));
typedef unsigned int u32;
typedef u32 u32x4 __attribute__((ext_vector_type(4)));

#define MFMA16(a, b, c) __builtin_amdgcn_mfma_f32_16x16x32_f16((a), (b), (c), 0, 0, 0)

#define HSZ 262144            // 512*512
#define LOGDET_C 235.2482644923962f  // 128*log(2*pi)

// ---- memory access primitives (all proven r3-r17) -------------------------
__device__ __forceinline__ void ld16_s(u32x4& d, const f16* p) {
    asm volatile("global_load_dwordx4 %0, %1, off sc0 sc1" : "=v"(d) : "v"(p));
}
__device__ __forceinline__ void ldf_n(float& d, const float* p) {
    asm volatile("global_load_dword %0, %1, off" : "=v"(d) : "v"(p));
}
__device__ __forceinline__ void st2_s(f16* p, f16 v) {
    u32 u = (u32)__builtin_bit_cast(unsigned short, v);
    asm volatile("global_store_short %0, %1, off sc0 sc1" :: "v"(p), "v"(u) : "memory");
}
__device__ __forceinline__ void sti_s(int* p, int v) {
    asm volatile("global_store_dword %0, %1, off sc0 sc1" :: "v"(p), "v"(v) : "memory");
}
__device__ __forceinline__ int ldi_s(const int* p) {
    int v;
    asm volatile("global_load_dword %0, %1, off sc0 sc1\ns_waitcnt vmcnt(0)"
                 : "=v"(v) : "v"(p) : "memory");
    return v;
}
// async global->LDS 16B (per-lane global src, wave-linear LDS dest)
__device__ __forceinline__ void gl16(const f16* g, char* l) {
    __builtin_amdgcn_global_load_lds(
        (const __attribute__((address_space(1))) u32*)g,
        (__attribute__((address_space(3))) u32*)l, 16, 0, 0);
}
// tanh via HW exp2+rcp: tanh(x) = 1 - 2/(exp2(x*2/ln2)+1). |err| ~1e-6.
__device__ __forceinline__ float tanh_fast(float x) {
    float e = __builtin_amdgcn_exp2f(x * 2.8853900817779268f);
    return 1.f - 2.f * __builtin_amdgcn_rcpf(e + 1.f);
}

// ---------------------------------------------------------------------------
// k_conv: conversions + small vectors; init slots=0.
__global__ void k_conv(const float* __restrict__ x, const float* __restrict__ mask,
                       const float* __restrict__ Wih0,
                       const float* __restrict__ b_ih0, const float* __restrict__ b_hh0,
                       const float* __restrict__ Whh0, const float* __restrict__ Wih1,
                       const float* __restrict__ Whh1, const float* __restrict__ W1,
                       const float* __restrict__ W2,
                       f16* __restrict__ A, f16* __restrict__ B1,
                       float* __restrict__ biasv,
                       f16* __restrict__ Whh0h, f16* __restrict__ Wih1h,
                       f16* __restrict__ Whh1h, f16* __restrict__ W1h,
                       f16* __restrict__ W2h, f16* __restrict__ h1all,
                       int* __restrict__ slots)
{
    int gid = blockIdx.x * 256 + threadIdx.x;   // 0..65535
    {
        int c = gid >> 7, k = gid & 127;
        A[gid]  = (f16)(x[gid] * mask[k]);
        B1[gid] = (f16)Wih0[c * 257 + 1 + k];
    }
    if (gid < 512) {
        float s = b_ih0[gid] + b_hh0[gid];
        const float* wrow = Wih0 + gid * 257 + 129;
        for (int k = 0; k < 128; k++) s += mask[k] * wrow[k];
        biasv[gid] = s;
    }
    for (int i = gid; i < 262144; i += 65536) {
        Whh0h[i] = (f16)Whh0[i];
        Wih1h[i] = (f16)Wih1[i];
        Whh1h[i] = (f16)Whh1[i];
        h1all[i] = (f16)0.f;      // h1[t=-1]
    }
    for (int i = gid; i < 1048576; i += 65536) W1h[i] = (f16)W1[i];
    for (int i = gid; i < 524288;  i += 65536) W2h[i] = (f16)W2[i];
    if (gid < 32768) slots[gid] = 0;
}

// ---------------------------------------------------------------------------
// k_base: base = A @ B1^T + biasv ; h0 slab0 = tanh(base)
__global__ __launch_bounds__(256) void k_base(const f16* __restrict__ A,
                                              const f16* __restrict__ B1,
                                              const float* __restrict__ biasv,
                                              float* __restrict__ base,
                                              f16* __restrict__ h0s0)
{
    __shared__ float part[4][32][32];
    int tid = threadIdx.x;
    int w = tid >> 6, l = tid & 63;
    int R0 = (blockIdx.x >> 4) * 32, C0 = (blockIdx.x & 15) * 32;
    int lr = l & 15, hi = l >> 4;

    const f16* a0p = A  + (R0 + lr) * 128 + w * 32 + hi * 8;
    const f16* b0p = B1 + (C0 + lr) * 128 + w * 32 + hi * 8;
    f16x8 a0 = *(const f16x8*)(a0p);
    f16x8 a1 = *(const f16x8*)(a0p + 16 * 128);
    f16x8 b0 = *(const f16x8*)(b0p);
    f16x8 b1 = *(const f16x8*)(b0p + 16 * 128);
    f32x4 z = {0.f, 0.f, 0.f, 0.f};
    f32x4 acc00 = MFMA16(a0, b0, z);
    f32x4 acc01 = MFMA16(a0, b1, z);
    f32x4 acc10 = MFMA16(a1, b0, z);
    f32x4 acc11 = MFMA16(a1, b1, z);
#pragma unroll
    for (int r = 0; r < 4; r++) {
        part[w][hi * 4 + r][lr]           = acc00[r];
        part[w][hi * 4 + r][16 + lr]      = acc01[r];
        part[w][16 + hi * 4 + r][lr]      = acc10[r];
        part[w][16 + hi * 4 + r][16 + lr] = acc11[r];
    }
    __syncthreads();
    int rr = tid >> 3, c0 = (tid & 7) * 4;
    int gr = R0 + rr;
#pragma unroll
    for (int cc = 0; cc < 4; cc++) {
        int gc = C0 + c0 + cc;
        float s = part[0][rr][c0 + cc] + part[1][rr][c0 + cc] +
                  part[2][rr][c0 + cc] + part[3][rr][c0 + cc] + biasv[gc];
        base[gr * 512 + gc] = s;
        h0s0[gr * 512 + gc] = (f16)tanh_fast(s);
    }
}

// ---------------------------------------------------------------------------
// Persistent recurrence kernel: EXACT r11 structure (proven 450-490 us).
#define LDH(off, f) (*(const f16x8*)((char*)Wl + (off) + lrowB + \
        ((((f) * 64 + hi16)) ^ lswz)))
#define LDB(m, f) (*(const f16x8*)((char*)Wl + \
        ((((m) * 32768 + colL * 1024 + (f) * 64 + hi16)) ^ cswz)))

#define RNN_STAGED()                                                          \
    for (int p = 0; p < 128; p++) {                                           \
        const f16* H0 = h0all + (size_t)p * HSZ;                              \
        const f16* H1 = h1all + (size_t)p * HSZ;                              \
        f16* H1o = h1all + (size_t)(p + 1) * HSZ;                             \
        f16* H0o = h0all + (size_t)(p + 1) * HSZ;                             \
        float xprev[4];                                                       \
        _Pragma("unroll")                                                     \
        for (int r = 0; r < 4; r++) ldf_n(xprev[r], x + (outrow + r) * 128 + p); \
        if (p) { int v; for (;;) { v = ldi_s(pollB); if (__all(v >= p)) break; \
                                   __builtin_amdgcn_s_sleep(1); } }           \
        _Pragma("unroll")                                                     \
        for (int i = 0; i < 8; i++) {                                         \
            int rr = w * 8 + i;                                               \
            gl16(H0 + (size_t)(R0 + rr) * 512 + ((l ^ (rr & 7)) * 8),         \
                 (char*)Wl + OFF_H0S + rr * 1024);                            \
        }                                                                     \
        asm volatile("s_waitcnt vmcnt(0)" ::: "memory");                      \
        __syncthreads();                                                      \
        f32x4 z4 = {0.f, 0.f, 0.f, 0.f};                                      \
        f32x4 a0a = z4, a0b = z4, a1a = z4, a1b = z4;                         \
        _Pragma("unroll")                                                     \
        for (int f = 0; f < 16; f += 2) {                                     \
            f16x8 A0 = LDH(OFF_H0S, f);                                       \
            f16x8 A1 = LDH(OFF_H0S, f + 1);                                   \
            a0a = MFMA16(A0, bW0[f],     a0a);                                \
            a0b = MFMA16(A1, bW0[f + 1], a0b);                                \
            a1a = MFMA16(A0, LDB(0, f),     a1a);                             \
            a1b = MFMA16(A1, LDB(0, f + 1), a1b);                             \
        }                                                                     \
        f32x4 acc0 = a0a + a0b;                                               \
        _Pragma("unroll")                                                     \
        for (int r = 0; r < 4; r++) {                                         \
            f16 v0 = (f16)tanh_fast(acc0[r] + basef[r] + xprev[r] * w0);      \
            st2_s(H0o + (outrow + r) * 512 + outcolg, v0);                    \
        }                                                                     \
        asm volatile("s_waitcnt vmcnt(0)" ::: "memory");                      \
        if (l == 0) sti_s(myB, p + 1);                                        \
        if (p) { int v; for (;;) { v = ldi_s(pollA); if (__all(v >= p)) break; \
                                   __builtin_amdgcn_s_sleep(1); } }           \
        _Pragma("unroll")                                                     \
        for (int i = 0; i < 8; i++) {                                         \
            int rr = w * 8 + i;                                               \
            gl16(H1 + (size_t)(R0 + rr) * 512 + ((l ^ (rr & 7)) * 8),         \
                 (char*)Wl + OFF_H1S + rr * 1024);                            \
        }                                                                     \
        asm volatile("s_waitcnt vmcnt(0)" ::: "memory");                      \
        __syncthreads();                                                      \
        _Pragma("unroll")                                                     \
        for (int f = 0; f < 16; f += 2) {                                     \
            a1a = MFMA16(LDH(OFF_H1S, f),     LDB(1, f),     a1a);            \
            a1b = MFMA16(LDH(OFF_H1S, f + 1), LDB(1, f + 1), a1b);            \
        }                                                                     \
        f32x4 acc1 = a1a + a1b;                                               \
        _Pragma("unroll")                                                     \
        for (int r = 0; r < 4; r++) {                                         \
            f16 v1 = (f16)tanh_fast(acc1[r] + bsum);                          \
            st2_s(H1o + (outrow + r) * 512 + outcolg, v1);                    \
        }                                                                     \
        asm volatile("s_waitcnt vmcnt(0)" ::: "memory");                      \
        if (l == 0) sti_s(myA, p + 1);                                        \
    }

// Fallback (2-slab h0 ring, small ws): r11's proven direct-load path.
#define RNN_DIRECT()                                                          \
    for (int p = 0; p < 128; p++) {                                           \
        const f16* H0 = h0all + (size_t)(p & 1) * HSZ;                        \
        const f16* H1 = h1all + (size_t)p * HSZ;                              \
        const f16* ap = H0 + (R0 + r_lo + lr) * 512 + hi * 8;                 \
        const f16* bp = H1 + (R0 + r_lo + lr) * 512 + hi * 8;                 \
        f16* H1o = h1all + (size_t)(p + 1) * HSZ;                             \
        f16* H0o = h0all + (size_t)((p + 1) & 1) * HSZ;                       \
        float xprev[4];                                                       \
        _Pragma("unroll")                                                     \
        for (int r = 0; r < 4; r++) ldf_n(xprev[r], x + (outrow + r) * 128 + p); \
        if (p) { int v; for (;;) { v = ldi_s(pollB); if (__all(v >= p)) break; \
                                   __builtin_amdgcn_s_sleep(1); } }           \
        u32x4 ra0[16], ra1[16];                                               \
        __builtin_amdgcn_sched_barrier(0);                                    \
        _Pragma("unroll")                                                     \
        for (int f = 0; f < 16; f++) ld16_s(ra0[f], ap + f * 32);             \
        asm volatile("s_waitcnt vmcnt(0)" ::: "memory");                      \
        __builtin_amdgcn_sched_barrier(0);                                    \
        f32x4 z4 = {0.f, 0.f, 0.f, 0.f};                                      \
        f32x4 a0a = z4, a0b = z4, a1a = z4, a1b = z4;                         \
        _Pragma("unroll")                                                     \
        for (int f = 0; f < 16; f += 2) {                                     \
            f16x8 A0 = __builtin_bit_cast(f16x8, ra0[f]);                     \
            f16x8 A1 = __builtin_bit_cast(f16x8, ra0[f + 1]);                 \
            a0a = MFMA16(A0, bW0[f],     a0a);                                \
            a0b = MFMA16(A1, bW0[f + 1], a0b);                                \
            a1a = MFMA16(A0, LDB(0, f),     a1a);                             \
            a1b = MFMA16(A1, LDB(0, f + 1), a1b);                             \
        }                                                                     \
        f32x4 acc0 = a0a + a0b;                                               \
        _Pragma("unroll")                                                     \
        for (int r = 0; r < 4; r++) {                                         \
            f16 v0 = (f16)tanh_fast(acc0[r] + basef[r] + xprev[r] * w0);      \
            st2_s(H0o + (outrow + r) * 512 + outcolg, v0);                    \
        }                                                                     \
        asm volatile("s_waitcnt vmcnt(0)" ::: "memory");                      \
        if (l == 0) sti_s(myB, p + 1);                                        \
        if (p) { int v; for (;;) { v = ldi_s(pollA); if (__all(v >= p)) break; \
                                   __builtin_amdgcn_s_sleep(1); } }           \
        __builtin_amdgcn_sched_barrier(0);                                    \
        _Pragma("unroll")                                                     \
        for (int f = 0; f < 16; f++) ld16_s(ra1[f], bp + f * 32);             \
        asm volatile("s_waitcnt vmcnt(0)" ::: "memory");                      \
        __builtin_amdgcn_sched_barrier(0);                                    \
        _Pragma("unroll")                                                     \
        for (int f = 0; f < 16; f += 2) {                                     \
            a1a = MFMA16(__builtin_bit_cast(f16x8, ra1[f]),     LDB(1, f),     a1a); \
            a1b = MFMA16(__builtin_bit_cast(f16x8, ra1[f + 1]), LDB(1, f + 1), a1b); \
        }                                                                     \
        f32x4 acc1 = a1a + a1b;                                               \
        _Pragma("unroll")                                                     \
        for (int r = 0; r < 4; r++) {                                         \
            f16 v1 = (f16)tanh_fast(acc1[r] + bsum);                          \
            st2_s(H1o + (outrow + r) * 512 + outcolg, v1);                    \
        }                                                                     \
        asm volatile("s_waitcnt vmcnt(0)" ::: "memory");                      \
        if (l == 0) sti_s(myA, p + 1);                                        \
    }

template<bool H0F>
__global__ __launch_bounds__(256, 1) void k_rnn(
    f16* __restrict__ h0all, f16* __restrict__ h1all,
    const f16* __restrict__ Whh0h, const f16* __restrict__ Wih1h,
    const f16* __restrict__ Whh1h,
    const float* __restrict__ base, const float* __restrict__ x,
    const float* __restrict__ Wih0, const float* __restrict__ b_ih1,
    const float* __restrict__ b_hh1, int* __restrict__ slots)
{
    const int OFF_H0S = 65536, OFF_H1S = 98304;
    __shared__ __align__(16) char Wl[131072];  // 64K weights + 32K h0s + 32K h1s
    int tid = threadIdx.x;
    int w = tid >> 6, l = tid & 63;
    int bid = blockIdx.x;
    int cluster = (bid & 7) * 2 + ((bid >> 3) & 1);   // cluster-mates share bid&7
    int cj = bid >> 4;
    int R0 = cluster * 32, C0 = cj * 32;

    // ---- stage Wih1/Whh1 col-slices into LDS with chunk-XOR swizzle
    {
        const f16* srcs[2] = { Wih1h, Whh1h };
        for (int m = 0; m < 2; m++) {
            const f16* S = srcs[m] + (size_t)C0 * 512;
            for (int cch = tid; cch < 2048; cch += 256) {
                int col = cch >> 6, kc = cch & 63;
                f16x8 v = *(const f16x8*)(S + col * 512 + kc * 8);
                int byte = m * 32768 + col * 1024 + kc * 16;
                byte ^= (col & 7) << 4;
                *(f16x8*)((char*)Wl + byte) = v;
            }
        }
    }
    __syncthreads();

    int lr = l & 15, hi = l >> 4;
    int r_lo = (w >> 1) * 16, c_lo = (w & 1) * 16;
    int outrow = R0 + r_lo + hi * 4;
    int outcolg = C0 + c_lo + lr;
    int colL = c_lo + lr;
    int lrow = r_lo + lr;
    int lrowB = lrow * 1024;
    int hi16 = hi * 16;
    int lswz = (lrow & 7) << 4;
    int cswz = (colL & 7) << 4;

    // ---- Whh0 B-fragments in registers (64 VGPR)
    f16x8 bW0[16];
    {
        const f16* w0p = Whh0h + (size_t)outcolg * 512 + hi * 8;
#pragma unroll
        for (int f = 0; f < 16; f++) bW0[f] = *(const f16x8*)(w0p + f * 32);
    }

    float basef[4];
#pragma unroll
    for (int r = 0; r < 4; r++) basef[r] = base[(outrow + r) * 512 + outcolg];
    float w0 = Wih0[outcolg * 257];
    float bsum = b_ih1[outcolg] + b_hh1[outcolg];

    // ---- per-wave slots (A = slots[0..16K), B = slots[16K..32K))
    int* slotA = slots;
    int* slotB = slots + 16384;
    int wslot = cj * 4 + w;
    int* myA = slotA + (cluster * 64 + wslot) * 16;
    int* myB = slotB + (cluster * 64 + wslot) * 16;
    const int* pollA = slotA + (cluster * 64 + l) * 16;
    const int* pollB = slotB + (cluster * 64 + l) * 16;

    if constexpr (H0F) {
        RNN_STAGED()           // monotonic slabs: staged plain reads, L3 stores
    } else {
        RNN_DIRECT()           // 2-slab ring: full L3 coherence
    }
}
#undef LDH
#undef LDB

// ---------------------------------------------------------------------------
// Phase B v5: v3's proven staging order (issue right after top barrier,
// before S3) + COUNTED-DRAIN barriers. __syncthreads' implicit vmcnt(0)
// (m97) was stalling barrier #2 on the fresh staging queue; raw s_barrier
// with lgkmcnt(0)-only at barrier #2 lets the 6 global_load_lds stay in
// flight across it — S3+S4 (~800cy) cover the latency; the only vmcnt(0)
// is at the top barrier where buf p must be resident anyway.
// Correctness: barriers wave-uniform; staging targets buf q (S3/S4 read
// buf p + hid only); sched_barrier(0) pins inline-asm wait ordering (r18).
__global__ __launch_bounds__(512, 2) void k_phaseB(const f16* __restrict__ h1all,
                                                   const f16* __restrict__ W1h,
                                                   const f16* __restrict__ W2h,
                                                   const float* __restrict__ b1v,
                                                   const float* __restrict__ b2,
                                                   const float* __restrict__ x,
                                                   float* __restrict__ pcontrib)
{
    __shared__ __align__(16) char Wl[108544];
    const int OFF_W2 = 65536, OFF_HID = 98304;

    int tid = threadIdx.x;
    int wv = tid >> 6, l = tid & 63;
    int lr = l & 15, hi = l >> 4;
    int M0 = blockIdx.x * 128;

    const f16* Hrow = h1all + HSZ + (size_t)(M0 + wv * 16 + lr) * 512;
    f16x8 afrag[16];
#pragma unroll
    for (int ks = 0; ks < 16; ks++)
        afrag[ks] = *(const f16x8*)(Hrow + ks * 32 + hi * 8);

    f32x4 mc[16] = {};

    // prologue: stage chunk 0 into buf 0
    {
#pragma unroll
        for (int it = 0; it < 4; it++) {
            int idx = it * 512 + tid;
            gl16(W1h + (size_t)(idx & 31) * 512 + (idx >> 5) * 8,
                 Wl + idx * 16);
        }
#pragma unroll
        for (int it = 0; it < 2; it++) {
            int idx = it * 512 + tid;
            gl16(W2h + (size_t)(idx & 255) * 2048 + (idx >> 8) * 8,
                 Wl + OFF_W2 + idx * 16);
        }
    }

    for (int c = 0; c < 64; c++) {
        int p = c & 1;
        // top barrier: staged buf p resident; hid free (S4 of c-1 done)
        asm volatile("s_waitcnt vmcnt(0) lgkmcnt(0)" ::: "memory");
        __builtin_amdgcn_sched_barrier(0);
        __builtin_amdgcn_s_barrier();
        __builtin_amdgcn_sched_barrier(0);

        if (c + 1 < 64) {  // stage next chunk into buf q (in flight thru bar2)
            const int nc = (c + 1) * 32, q = p ^ 1;
#pragma unroll
            for (int it = 0; it < 4; it++) {
                int idx = it * 512 + tid;
                gl16(W1h + (size_t)(nc + (idx & 31)) * 512 + (idx >> 5) * 8,
                     Wl + q * 32768 + idx * 16);
            }
#pragma unroll
            for (int it = 0; it < 2; it++) {
                int idx = it * 512 + tid;
                gl16(W2h + (size_t)(idx & 255) * 2048 + nc + (idx >> 8) * 8,
                     Wl + OFF_W2 + q * 16384 + idx * 16);
            }
        }

        // ---- S3: hid[128][32] = relu(H_tile @ W1c^T + b1)
        {
            f32x4 s3a = {0.f, 0.f, 0.f, 0.f}, s3b = s3a;
#pragma unroll
            for (int ks = 0; ks < 16; ks++) {
                f16x8 wb0 = *(const f16x8*)(Wl + p * 32768 +
                                            ((ks * 4 + hi) * 32 + lr) * 16);
                f16x8 wb1 = *(const f16x8*)(Wl + p * 32768 +
                                            ((ks * 4 + hi) * 32 + 16 + lr) * 16);
                s3a = MFMA16(afrag[ks], wb0, s3a);
                s3b = MFMA16(afrag[ks], wb1, s3b);
            }
            float bb0 = b1v[c * 32 + lr];
            float bb1 = b1v[c * 32 + 16 + lr];
#pragma unroll
            for (int r = 0; r < 4; r++) {
                int lrow = wv * 16 + hi * 4 + r;
                *(f16*)(Wl + OFF_HID + (lrow * 40 + lr) * 2) =
                    (f16)fmaxf(s3a[r] + bb0, 0.f);
                *(f16*)(Wl + OFF_HID + (lrow * 40 + 16 + lr) * 2) =
                    (f16)fmaxf(s3b[r] + bb1, 0.f);
            }
        }
        // barrier #2: hid complete. DS-only drain — staging stays in flight.
        asm volatile("s_waitcnt lgkmcnt(0)" ::: "memory");
        __builtin_amdgcn_sched_barrier(0);
        __builtin_amdgcn_s_barrier();
        __builtin_amdgcn_sched_barrier(0);

        // ---- S4: mc[16 rows][256] += hid(own rows) @ W2c^T
        {
            f16x8 a = *(const f16x8*)(Wl + OFF_HID +
                                      ((wv * 16 + lr) * 40 + hi * 8) * 2);
#pragma unroll
            for (int cf = 0; cf < 16; cf++) {
                f16x8 b = *(const f16x8*)(Wl + OFF_W2 + p * 16384 +
                                          (hi * 256 + cf * 16 + lr) * 16);
                mc[cf] = MFMA16(a, b, mc[cf]);
            }
        }
    }

    // ---- epilogue: GMM log-prob
    float quad[4] = {}, ls[4] = {}, xt[4];
#pragma unroll
    for (int r = 0; r < 4; r++) {
        int m = M0 + wv * 16 + hi * 4 + r;
        xt[r] = x[(m & 511) * 128 + (m >> 9)];
    }
#pragma unroll
    for (int cf = 0; cf < 8; cf++) {
        int cc = cf * 16 + lr;
        float bm = b2[cc], bc = b2[128 + cc];
#pragma unroll
        for (int r = 0; r < 4; r++) {
            float mean = mc[cf][r] + bm;
            float cov  = mc[cf + 8][r] + bc;
            float sp = log1pf(expf(-fabsf(cov))) + fmaxf(cov, 0.f);
            float d = xt[r] - mean;
            quad[r] += d * d * sp;
            ls[r] += logf(sp);
        }
    }
#pragma unroll
    for (int mm = 1; mm < 16; mm <<= 1)
#pragma unroll
        for (int r = 0; r < 4; r++) {
            quad[r] += __shfl_xor(quad[r], mm, 64);
            ls[r]   += __shfl_xor(ls[r], mm, 64);
        }
    if (lr == 0) {
#pragma unroll
        for (int r = 0; r < 4; r++) {
            int m = M0 + wv * 16 + hi * 4 + r;
            pcontrib[m] = -0.5f * (LOGDET_C + quad[r]) - 0.5f * ls[r];
        }
    }
}

// ---------------------------------------------------------------------------
__global__ void k_fin(const f16* __restrict__ h1last,
                      const float* __restrict__ pcontrib, float* __restrict__ out)
{
    int gid = blockIdx.x * 256 + threadIdx.x;
    for (int i = gid; i < HSZ; i += 131072) out[i] = (float)h1last[i];
    if (gid < 512) {
        float s = 0.f;
        for (int tt = 0; tt < 128; tt++) s += pcontrib[tt * 512 + gid];
        out[HSZ + gid] = s;
    }
}

// ---------------------------------------------------------------------------
extern "C" void kernel_launch(void* const* d_in, const int* in_sizes, int n_in,
                              void* d_out, int out_size, void* d_ws, size_t ws_size,
                              hipStream_t stream) {
    const float* x     = (const float*)d_in[0];
    const float* mask  = (const float*)d_in[1];
    const float* Wih0  = (const float*)d_in[2];
    const float* Whh0  = (const float*)d_in[3];
    const float* b_ih0 = (const float*)d_in[4];
    const float* b_hh0 = (const float*)d_in[5];
    const float* Wih1  = (const float*)d_in[6];
    const float* Whh1  = (const float*)d_in[7];
    const float* b_ih1 = (const float*)d_in[8];
    const float* b_hh1 = (const float*)d_in[9];
    const float* W1    = (const float*)d_in[10];
    const float* b1    = (const float*)d_in[11];
    const float* W2    = (const float*)d_in[12];
    const float* b2    = (const float*)d_in[13];

    char* ws = (char*)d_ws;
    size_t off = 0;
    auto take = [&](size_t bytes) { char* p = ws + off; off += (bytes + 255) & ~(size_t)255; return p; };
    float* base    = (float*)take(512 * 512 * 4);
    f16* Whh0h     = (f16*)take(HSZ * 2);
    f16* Wih1h     = (f16*)take(HSZ * 2);
    f16* Whh1h     = (f16*)take(HSZ * 2);
    f16* W1h       = (f16*)take(1048576 * 2);
    f16* W2h       = (f16*)take(524288 * 2);
    f16* h0buf     = (f16*)take(2 * HSZ * 2);
    f16* h1all     = (f16*)take((size_t)129 * HSZ * 2);
    float* pcontrib= (float*)take(128 * 512 * 4);
    f16* A         = (f16*)take(65536 * 2);
    f16* B1        = (f16*)take(65536 * 2);
    float* biasv   = (float*)take(512 * 4);
    int* slots     = (int*)take(32768 * 4);
    if (off > ws_size) return;

    // Optional monotonic h0 slabs (66 MB): enables cached/virgin h0 reads.
    const size_t h0all_bytes = (size_t)129 * HSZ * 2;
    bool big = (off + h0all_bytes + 256 <= ws_size);
    f16* h0all = big ? (f16*)take(h0all_bytes) : h0buf;

    k_conv<<<256, 256, 0, stream>>>(x, mask, Wih0, b_ih0, b_hh0, Whh0, Wih1, Whh1,
                                    W1, W2, A, B1, biasv, Whh0h, Wih1h, Whh1h,
                                    W1h, W2h, h1all, slots);
    k_base<<<256, 256, 0, stream>>>(A, B1, biasv, base, h0all);
    if (big)
        k_rnn<true><<<256, 256, 0, stream>>>(h0all, h1all, Whh0h, Wih1h, Whh1h,
                                             base, x, Wih0, b_ih1, b_hh1, slots);
    else
        k_rnn<false><<<256, 256, 0, stream>>>(h0all, h1all, Whh0h, Wih1h, Whh1h,
                                              base, x, Wih0, b_ih1, b_hh1, slots);
    k_phaseB<<<512, 512, 0, stream>>>(h1all, W1h, W2h, b1, b2, x, pcontrib);
    k_fin<<<512, 256, 0, stream>>>(h1all + (size_t)128 * HSZ, pcontrib, (float*)d_out);
}

// Round 19
// 749.526 us; speedup vs baseline: 1.1565x; 1.1128x over previous
//
#include <hip/hip_runtime.h>

typedef _Float16 f16;
typedef _Float16 f16x8 __attribute__((ext_vector_type(8)));
typedef float    f32x4 __attribute__((ext_vector_type(4)));
typedef unsigned int u32;
typedef u32 u32x4 __attribute__((ext_vector_type(4)));
typedef unsigned long long u64;

#define MFMA16(a, b, c) __builtin_amdgcn_mfma_f32_16x16x32_f16((a), (b), (c), 0, 0, 0)

#define HSZ 262144            // 512*512
#define LOGDET_C 235.2482644923962f  // 128*log(2*pi)

// ---- memory access primitives -------------------------------------------
__device__ __forceinline__ void ld16_s(u32x4& d, const f16* p) {
    asm volatile("global_load_dwordx4 %0, %1, off sc0 sc1" : "=v"(d) : "v"(p));
}
__device__ __forceinline__ void ldf_n(float& d, const float* p) {
    asm volatile("global_load_dword %0, %1, off" : "=v"(d) : "v"(p));
}
__device__ __forceinline__ void st2_n(f16* p, f16 v) {
    u32 u = (u32)__builtin_bit_cast(unsigned short, v);
    asm volatile("global_store_short %0, %1, off" :: "v"(p), "v"(u) : "memory");
}
__device__ __forceinline__ void st2_s(f16* p, f16 v) {
    u32 u = (u32)__builtin_bit_cast(unsigned short, v);
    asm volatile("global_store_short %0, %1, off sc0 sc1" :: "v"(p), "v"(u) : "memory");
}
__device__ __forceinline__ void sti_s(int* p, int v) {
    asm volatile("global_store_dword %0, %1, off sc0 sc1" :: "v"(p), "v"(v) : "memory");
}
__device__ __forceinline__ int ldi_s(const int* p) {
    int v;
    asm volatile("global_load_dword %0, %1, off sc0 sc1\ns_waitcnt vmcnt(0)"
                 : "=v"(v) : "v"(p) : "memory");
    return v;
}
// async global->LDS 16B (per-lane global src, wave-linear LDS dest)
__device__ __forceinline__ void gl16(const f16* g, char* l) {
    __builtin_amdgcn_global_load_lds(
        (const __attribute__((address_space(1))) u32*)g,
        (__attribute__((address_space(3))) u32*)l, 16, 0, 0);
}
// tanh via HW exp2+rcp: tanh(x) = 1 - 2/(exp2(x*2/ln2)+1). |err| ~1e-6.
__device__ __forceinline__ float tanh_fast(float x) {
    float e = __builtin_amdgcn_exp2f(x * 2.8853900817779268f);
    return 1.f - 2.f * __builtin_amdgcn_rcpf(e + 1.f);
}

// ---------------------------------------------------------------------------
// k_conv: conversions + small vectors; init slots=0, xcdtab=-1.
__global__ void k_conv(const float* __restrict__ x, const float* __restrict__ mask,
                       const float* __restrict__ Wih0,
                       const float* __restrict__ b_ih0, const float* __restrict__ b_hh0,
                       const float* __restrict__ Whh0, const float* __restrict__ Wih1,
                       const float* __restrict__ Whh1, const float* __restrict__ W1,
                       const float* __restrict__ W2,
                       f16* __restrict__ A, f16* __restrict__ B1,
                       float* __restrict__ biasv,
                       f16* __restrict__ Whh0h, f16* __restrict__ Wih1h,
                       f16* __restrict__ Whh1h, f16* __restrict__ W1h,
                       f16* __restrict__ W2h, f16* __restrict__ h1all,
                       int* __restrict__ slots, int* __restrict__ xcdtab)
{
    int gid = blockIdx.x * 256 + threadIdx.x;   // 0..65535
    {
        int c = gid >> 7, k = gid & 127;
        A[gid]  = (f16)(x[gid] * mask[k]);
        B1[gid] = (f16)Wih0[c * 257 + 1 + k];
    }
    if (gid < 512) {
        float s = b_ih0[gid] + b_hh0[gid];
        const float* wrow = Wih0 + gid * 257 + 129;
        for (int k = 0; k < 128; k++) s += mask[k] * wrow[k];
        biasv[gid] = s;
    }
    for (int i = gid; i < 262144; i += 65536) {
        Whh0h[i] = (f16)Whh0[i];
        Wih1h[i] = (f16)Wih1[i];
        Whh1h[i] = (f16)Whh1[i];
        h1all[i] = (f16)0.f;      // h1[t=-1]
    }
    for (int i = gid; i < 1048576; i += 65536) W1h[i] = (f16)W1[i];
    for (int i = gid; i < 524288;  i += 65536) W2h[i] = (f16)W2[i];
    if (gid < 32768) slots[gid] = 0;
    if (gid < 4096)  xcdtab[gid] = -1;
}

// ---------------------------------------------------------------------------
// k_base: base = A @ B1^T + biasv ; h0 slab0 = tanh(base)
__global__ __launch_bounds__(256) void k_base(const f16* __restrict__ A,
                                              const f16* __restrict__ B1,
                                              const float* __restrict__ biasv,
                                              float* __restrict__ base,
                                              f16* __restrict__ h0s0)
{
    __shared__ float part[4][32][32];
    int tid = threadIdx.x;
    int w = tid >> 6, l = tid & 63;
    int R0 = (blockIdx.x >> 4) * 32, C0 = (blockIdx.x & 15) * 32;
    int lr = l & 15, hi = l >> 4;

    const f16* a0p = A  + (R0 + lr) * 128 + w * 32 + hi * 8;
    const f16* b0p = B1 + (C0 + lr) * 128 + w * 32 + hi * 8;
    f16x8 a0 = *(const f16x8*)(a0p);
    f16x8 a1 = *(const f16x8*)(a0p + 16 * 128);
    f16x8 b0 = *(const f16x8*)(b0p);
    f16x8 b1 = *(const f16x8*)(b0p + 16 * 128);
    f32x4 z = {0.f, 0.f, 0.f, 0.f};
    f32x4 acc00 = MFMA16(a0, b0, z);
    f32x4 acc01 = MFMA16(a0, b1, z);
    f32x4 acc10 = MFMA16(a1, b0, z);
    f32x4 acc11 = MFMA16(a1, b1, z);
#pragma unroll
    for (int r = 0; r < 4; r++) {
        part[w][hi * 4 + r][lr]           = acc00[r];
        part[w][hi * 4 + r][16 + lr]      = acc01[r];
        part[w][16 + hi * 4 + r][lr]      = acc10[r];
        part[w][16 + hi * 4 + r][16 + lr] = acc11[r];
    }
    __syncthreads();
    int rr = tid >> 3, c0 = (tid & 7) * 4;
    int gr = R0 + rr;
#pragma unroll
    for (int cc = 0; cc < 4; cc++) {
        int gc = C0 + c0 + cc;
        float s = part[0][rr][c0 + cc] + part[1][rr][c0 + cc] +
                  part[2][rr][c0 + cc] + part[3][rr][c0 + cc] + biasv[gc];
        base[gr * 512 + gc] = s;
        h0s0[gr * 512 + gc] = (f16)tanh_fast(s);
    }
}

// ---------------------------------------------------------------------------
// Persistent recurrence kernel v11 = r11's proven 450-us body + atomic-free
// publish-table roster for XCD-local clustering.
#define LDH(off, f) (*(const f16x8*)((char*)Wl + (off) + lrowB + \
        ((((f) * 64 + hi16)) ^ lswz)))
#define LDB(m, f) (*(const f16x8*)((char*)Wl + \
        ((((m) * 32768 + colL * 1024 + (f) * 64 + hi16)) ^ cswz)))

#define RNN_STAGED(ST2x)                                                      \
    for (int p = 0; p < 128; p++) {                                           \
        const f16* H0 = h0all + (size_t)(p & PMASK) * HSZ;                    \
        const f16* H1 = h1all + (size_t)p * HSZ;                              \
        f16* H1o = h1all + (size_t)(p + 1) * HSZ;                             \
        f16* H0o = h0all + (size_t)((p + 1) & PMASK) * HSZ;                   \
        float xprev[4];                                                       \
        _Pragma("unroll")                                                     \
        for (int r = 0; r < 4; r++) ldf_n(xprev[r], x + (outrow + r) * 128 + p); \
        if (p) { int v; for (;;) { v = ldi_s(pollB); if (__all(v >= p)) break; \
                                   __builtin_amdgcn_s_sleep(1); } }           \
        _Pragma("unroll")                                                     \
        for (int i = 0; i < 8; i++) {                                         \
            int rr = w * 8 + i;                                               \
            gl16(H0 + (size_t)(R0 + rr) * 512 + ((l ^ (rr & 7)) * 8),         \
                 (char*)Wl + OFF_H0S + rr * 1024);                            \
        }                                                                     \
        asm volatile("s_waitcnt vmcnt(0)" ::: "memory");                      \
        __syncthreads();                                                      \
        f32x4 z4 = {0.f, 0.f, 0.f, 0.f};                                      \
        f32x4 a0a = z4, a0b = z4, a1a = z4, a1b = z4;                         \
        _Pragma("unroll")                                                     \
        for (int f = 0; f < 16; f += 2) {                                     \
            f16x8 A0 = LDH(OFF_H0S, f);                                       \
            f16x8 A1 = LDH(OFF_H0S, f + 1);                                   \
            a0a = MFMA16(A0, bW0[f],     a0a);                                \
            a0b = MFMA16(A1, bW0[f + 1], a0b);                                \
            a1a = MFMA16(A0, LDB(0, f),     a1a);                             \
            a1b = MFMA16(A1, LDB(0, f + 1), a1b);                             \
        }                                                                     \
        f32x4 acc0 = a0a + a0b;                                               \
        _Pragma("unroll")                                                     \
        for (int r = 0; r < 4; r++) {                                         \
            f16 v0 = (f16)tanh_fast(acc0[r] + basef[r] + xprev[r] * w0);      \
            ST2x(H0o + (outrow + r) * 512 + outcolg, v0);                     \
        }                                                                     \
        asm volatile("s_waitcnt vmcnt(0)" ::: "memory");                      \
        if (l == 0) sti_s(myB, p + 1);                                        \
        if (p) { int v; for (;;) { v = ldi_s(pollA); if (__all(v >= p)) break; \
                                   __builtin_amdgcn_s_sleep(1); } }           \
        _Pragma("unroll")                                                     \
        for (int i = 0; i < 8; i++) {                                         \
            int rr = w * 8 + i;                                               \
            gl16(H1 + (size_t)(R0 + rr) * 512 + ((l ^ (rr & 7)) * 8),         \
                 (char*)Wl + OFF_H1S + rr * 1024);                            \
        }                                                                     \
        asm volatile("s_waitcnt vmcnt(0)" ::: "memory");                      \
        __syncthreads();                                                      \
        _Pragma("unroll")                                                     \
        for (int f = 0; f < 16; f += 2) {                                     \
            a1a = MFMA16(LDH(OFF_H1S, f),     LDB(1, f),     a1a);            \
            a1b = MFMA16(LDH(OFF_H1S, f + 1), LDB(1, f + 1), a1b);            \
        }                                                                     \
        f32x4 acc1 = a1a + a1b;                                               \
        _Pragma("unroll")                                                     \
        for (int r = 0; r < 4; r++) {                                         \
            f16 v1 = (f16)tanh_fast(acc1[r] + bsum);                          \
            ST2x(H1o + (outrow + r) * 512 + outcolg, v1);                     \
        }                                                                     \
        asm volatile("s_waitcnt vmcnt(0)" ::: "memory");                      \
        if (l == 0) sti_s(myA, p + 1);                                        \
    }

// Fallback (2-slab h0 ring): proven direct-load path, sc0 sc1.
#define RNN_DIRECT()                                                          \
    for (int p = 0; p < 128; p++) {                                           \
        const f16* H0 = h0all + (size_t)(p & PMASK) * HSZ;                    \
        const f16* H1 = h1all + (size_t)p * HSZ;                              \
        const f16* ap = H0 + (R0 + r_lo + lr) * 512 + hi * 8;                 \
        const f16* bp = H1 + (R0 + r_lo + lr) * 512 + hi * 8;                 \
        f16* H1o = h1all + (size_t)(p + 1) * HSZ;                             \
        f16* H0o = h0all + (size_t)((p + 1) & PMASK) * HSZ;                   \
        float xprev[4];                                                       \
        _Pragma("unroll")                                                     \
        for (int r = 0; r < 4; r++) ldf_n(xprev[r], x + (outrow + r) * 128 + p); \
        if (p) { int v; for (;;) { v = ldi_s(pollB); if (__all(v >= p)) break; \
                                   __builtin_amdgcn_s_sleep(1); } }           \
        u32x4 ra0[16], ra1[16];                                               \
        __builtin_amdgcn_sched_barrier(0);                                    \
        _Pragma("unroll")                                                     \
        for (int f = 0; f < 16; f++) ld16_s(ra0[f], ap + f * 32);             \
        asm volatile("s_waitcnt vmcnt(0)" ::: "memory");                      \
        __builtin_amdgcn_sched_barrier(0);                                    \
        f32x4 z4 = {0.f, 0.f, 0.f, 0.f};                                      \
        f32x4 a0a = z4, a0b = z4, a1a = z4, a1b = z4;                         \
        _Pragma("unroll")                                                     \
        for (int f = 0; f < 16; f += 2) {                                     \
            f16x8 A0 = __builtin_bit_cast(f16x8, ra0[f]);                     \
            f16x8 A1 = __builtin_bit_cast(f16x8, ra0[f + 1]);                 \
            a0a = MFMA16(A0, bW0[f],     a0a);                                \
            a0b = MFMA16(A1, bW0[f + 1], a0b);                                \
            a1a = MFMA16(A0, LDB(0, f),     a1a);                             \
            a1b = MFMA16(A1, LDB(0, f + 1), a1b);                             \
        }                                                                     \
        f32x4 acc0 = a0a + a0b;                                               \
        _Pragma("unroll")                                                     \
        for (int r = 0; r < 4; r++) {                                         \
            f16 v0 = (f16)tanh_fast(acc0[r] + basef[r] + xprev[r] * w0);      \
            st2_s(H0o + (outrow + r) * 512 + outcolg, v0);                    \
        }                                                                     \
        asm volatile("s_waitcnt vmcnt(0)" ::: "memory");                      \
        if (l == 0) sti_s(myB, p + 1);                                        \
        if (p) { int v; for (;;) { v = ldi_s(pollA); if (__all(v >= p)) break; \
                                   __builtin_amdgcn_s_sleep(1); } }           \
        __builtin_amdgcn_sched_barrier(0);                                    \
        _Pragma("unroll")                                                     \
        for (int f = 0; f < 16; f++) ld16_s(ra1[f], bp + f * 32);             \
        asm volatile("s_waitcnt vmcnt(0)" ::: "memory");                      \
        __builtin_amdgcn_sched_barrier(0);                                    \
        _Pragma("unroll")                                                     \
        for (int f = 0; f < 16; f += 2) {                                     \
            a1a = MFMA16(__builtin_bit_cast(f16x8, ra1[f]),     LDB(1, f),     a1a); \
            a1b = MFMA16(__builtin_bit_cast(f16x8, ra1[f + 1]), LDB(1, f + 1), a1b); \
        }                                                                     \
        f32x4 acc1 = a1a + a1b;                                               \
        _Pragma("unroll")                                                     \
        for (int r = 0; r < 4; r++) {                                         \
            f16 v1 = (f16)tanh_fast(acc1[r] + bsum);                          \
            st2_s(H1o + (outrow + r) * 512 + outcolg, v1);                    \
        }                                                                     \
        asm volatile("s_waitcnt vmcnt(0)" ::: "memory");                      \
        if (l == 0) sti_s(myA, p + 1);                                        \
    }

template<bool H0F>
__global__ __launch_bounds__(256, 1) void k_rnn(
    f16* __restrict__ h0all, f16* __restrict__ h1all,
    const f16* __restrict__ Whh0h, const f16* __restrict__ Wih1h,
    const f16* __restrict__ Whh1h,
    const float* __restrict__ base, const float* __restrict__ x,
    const float* __restrict__ Wih0, const float* __restrict__ b_ih1,
    const float* __restrict__ b_hh1, int* __restrict__ slots,
    int* __restrict__ xcdtab)
{
    constexpr int PMASK = H0F ? 255 : 1;
    const int OFF_H0S = 65536, OFF_H1S = 98304;
    __shared__ __align__(16) char Wl[131072];  // 64K weights + 32K h0s + 32K h1s
    __shared__ int s_mode, s_cluster, s_cj;
    int tid = threadIdx.x;
    int w = tid >> 6, l = tid & 63;
    int bid = blockIdx.x;

    int xcdreg;
    asm("s_getreg_b32 %0, hwreg(20, 0, 32)" : "=s"(xcdreg));  // HW_REG_XCC_ID
    int xcc = xcdreg & 7;

    // ---- publish-table roster (atomic-free; uniform-exit waits only)
    if constexpr (H0F) {
        if (tid == 0) sti_s(xcdtab + bid * 16, xcc);
        if (w == 0) {
            int e[4];
            for (;;) {
                bool neg = false;
#pragma unroll
                for (int g = 0; g < 4; g++) {
                    e[g] = ldi_s(xcdtab + (g * 64 + l) * 16);
                    neg |= (e[g] < 0);
                }
                if (!__any(neg)) break;               // uniform exit
                __builtin_amdgcn_s_sleep(1);
            }
            int ok = 1;
#pragma unroll
            for (int k = 0; k < 8; k++) {
                int cnt = 0;
#pragma unroll
                for (int g = 0; g < 4; g++)
                    cnt += __popcll(__ballot(e[g] == k));
                if (cnt != 32) ok = 0;
            }
            int rank = 0;
#pragma unroll
            for (int g = 0; g < 4; g++) {
                u64 m = __ballot(e[g] == xcc);
                int b0 = g * 64;
                u64 lt = (bid <= b0) ? 0ull
                       : (bid >= b0 + 64) ? ~0ull
                       : ((1ull << (bid - b0)) - 1);
                rank += __popcll(m & lt);
            }
            if (l == 0) {
                s_mode = ok;
                s_cluster = ok ? (xcc * 2 + (rank >> 4))
                               : ((bid & 7) * 2 + ((bid >> 3) & 1));
                s_cj = ok ? (rank & 15) : (bid >> 4);
            }
        }
        __syncthreads();
    } else {
        if (tid == 0) {
            s_mode = 0;
            s_cluster = (bid & 7) * 2 + ((bid >> 3) & 1);
            s_cj = bid >> 4;
        }
        __syncthreads();
    }
    const bool fast = (s_mode != 0);
    int cluster = s_cluster, cj = s_cj;
    int R0 = cluster * 32, C0 = cj * 32;

    // ---- stage Wih1/Whh1 col-slices into LDS with chunk-XOR swizzle (r11)
    {
        const f16* srcs[2] = { Wih1h, Whh1h };
        for (int m = 0; m < 2; m++) {
            const f16* S = srcs[m] + (size_t)C0 * 512;
            for (int cch = tid; cch < 2048; cch += 256) {
                int col = cch >> 6, kc = cch & 63;
                f16x8 v = *(const f16x8*)(S + col * 512 + kc * 8);
                int byte = m * 32768 + col * 1024 + kc * 16;
                byte ^= (col & 7) << 4;
                *(f16x8*)((char*)Wl + byte) = v;
            }
        }
    }
    __syncthreads();

    int lr = l & 15, hi = l >> 4;
    int r_lo = (w >> 1) * 16, c_lo = (w & 1) * 16;
    int outrow = R0 + r_lo + hi * 4;
    int outcolg = C0 + c_lo + lr;
    int colL = c_lo + lr;
    int lrow = r_lo + lr;
    int lrowB = lrow * 1024;
    int hi16 = hi * 16;
    int lswz = (lrow & 7) << 4;
    int cswz = (colL & 7) << 4;

    // ---- Whh0 B-fragments in registers (64 VGPR)
    f16x8 bW0[16];
    {
        const f16* w0p = Whh0h + (size_t)outcolg * 512 + hi * 8;
#pragma unroll
        for (int f = 0; f < 16; f++) bW0[f] = *(const f16x8*)(w0p + f * 32);
    }

    float basef[4];
#pragma unroll
    for (int r = 0; r < 4; r++) basef[r] = base[(outrow + r) * 512 + outcolg];
    float w0 = Wih0[outcolg * 257];
    float bsum = b_ih1[outcolg] + b_hh1[outcolg];

    // ---- per-wave slots (A = slots[0..16K), B = slots[16K..32K))
    int* slotA = slots;
    int* slotB = slots + 16384;
    int wslot = cj * 4 + w;
    int* myA = slotA + (cluster * 64 + wslot) * 16;
    int* myB = slotB + (cluster * 64 + wslot) * 16;
    const int* pollA = slotA + (cluster * 64 + l) * 16;
    const int* pollB = slotB + (cluster * 64 + l) * 16;

    if (H0F && fast) {
        RNN_STAGED(st2_n)      // XCD-local by construction: L2 exchange
    } else if (H0F) {
        RNN_STAGED(st2_s)      // virgin slabs: plain staged reads, L3 stores
    } else {
        RNN_DIRECT()           // 2-slab ring: full L3 coherence
    }
}
#undef LDH
#undef LDB

// ---------------------------------------------------------------------------
// Phase B v3 (proven best ordering)
__global__ __launch_bounds__(512, 2) void k_phaseB(const f16* __restrict__ h1all,
                                                   const f16* __restrict__ W1h,
                                                   const f16* __restrict__ W2h,
                                                   const float* __restrict__ b1v,
                                                   const float* __restrict__ b2,
                                                   const float* __restrict__ x,
                                                   float* __restrict__ pcontrib)
{
    __shared__ __align__(16) char Wl[108544];
    const int OFF_W2 = 65536, OFF_HID = 98304;

    int tid = threadIdx.x;
    int wv = tid >> 6, l = tid & 63;
    int lr = l & 15, hi = l >> 4;
    int M0 = blockIdx.x * 128;

    const f16* Hrow = h1all + HSZ + (size_t)(M0 + wv * 16 + lr) * 512;
    f16x8 afrag[16];
#pragma unroll
    for (int ks = 0; ks < 16; ks++)
        afrag[ks] = *(const f16x8*)(Hrow + ks * 32 + hi * 8);

    f32x4 mc[16] = {};

    {
#pragma unroll
        for (int it = 0; it < 4; it++) {
            int idx = it * 512 + tid;
            gl16(W1h + (size_t)(idx & 31) * 512 + (idx >> 5) * 8,
                 Wl + idx * 16);
        }
#pragma unroll
        for (int it = 0; it < 2; it++) {
            int idx = it * 512 + tid;
            gl16(W2h + (size_t)(idx & 255) * 2048 + (idx >> 8) * 8,
                 Wl + OFF_W2 + idx * 16);
        }
    }

    for (int c = 0; c < 64; c++) {
        int p = c & 1;
        __syncthreads();

        if (c + 1 < 64) {
            const int nc = (c + 1) * 32, q = p ^ 1;
#pragma unroll
            for (int it = 0; it < 4; it++) {
                int idx = it * 512 + tid;
                gl16(W1h + (size_t)(nc + (idx & 31)) * 512 + (idx >> 5) * 8,
                     Wl + q * 32768 + idx * 16);
            }
#pragma unroll
            for (int it = 0; it < 2; it++) {
                int idx = it * 512 + tid;
                gl16(W2h + (size_t)(idx & 255) * 2048 + nc + (idx >> 8) * 8,
                     Wl + OFF_W2 + q * 16384 + idx * 16);
            }
        }

        {
            f32x4 s3a = {0.f, 0.f, 0.f, 0.f}, s3b = s3a;
#pragma unroll
            for (int ks = 0; ks < 16; ks++) {
                f16x8 wb0 = *(const f16x8*)(Wl + p * 32768 +
                                            ((ks * 4 + hi) * 32 + lr) * 16);
                f16x8 wb1 = *(const f16x8*)(Wl + p * 32768 +
                                            ((ks * 4 + hi) * 32 + 16 + lr) * 16);
                s3a = MFMA16(afrag[ks], wb0, s3a);
                s3b = MFMA16(afrag[ks], wb1, s3b);
            }
            float bb0 = b1v[c * 32 + lr];
            float bb1 = b1v[c * 32 + 16 + lr];
#pragma unroll
            for (int r = 0; r < 4; r++) {
                int lrow = wv * 16 + hi * 4 + r;
                *(f16*)(Wl + OFF_HID + (lrow * 40 + lr) * 2) =
                    (f16)fmaxf(s3a[r] + bb0, 0.f);
                *(f16*)(Wl + OFF_HID + (lrow * 40 + 16 + lr) * 2) =
                    (f16)fmaxf(s3b[r] + bb1, 0.f);
            }
        }
        __syncthreads();

        {
            f16x8 a = *(const f16x8*)(Wl + OFF_HID +
                                      ((wv * 16 + lr) * 40 + hi * 8) * 2);
#pragma unroll
            for (int cf = 0; cf < 16; cf++) {
                f16x8 b = *(const f16x8*)(Wl + OFF_W2 + p * 16384 +
                                          (hi * 256 + cf * 16 + lr) * 16);
                mc[cf] = MFMA16(a, b, mc[cf]);
            }
        }
    }

    float quad[4] = {}, ls[4] = {}, xt[4];
#pragma unroll
    for (int r = 0; r < 4; r++) {
        int m = M0 + wv * 16 + hi * 4 + r;
        xt[r] = x[(m & 511) * 128 + (m >> 9)];
    }
#pragma unroll
    for (int cf = 0; cf < 8; cf++) {
        int cc = cf * 16 + lr;
        float bm = b2[cc], bc = b2[128 + cc];
#pragma unroll
        for (int r = 0; r < 4; r++) {
            float mean = mc[cf][r] + bm;
            float cov  = mc[cf + 8][r] + bc;
            float sp = log1pf(expf(-fabsf(cov))) + fmaxf(cov, 0.f);
            float d = xt[r] - mean;
            quad[r] += d * d * sp;
            ls[r] += logf(sp);
        }
    }
#pragma unroll
    for (int mm = 1; mm < 16; mm <<= 1)
#pragma unroll
        for (int r = 0; r < 4; r++) {
            quad[r] += __shfl_xor(quad[r], mm, 64);
            ls[r]   += __shfl_xor(ls[r], mm, 64);
        }
    if (lr == 0) {
#pragma unroll
        for (int r = 0; r < 4; r++) {
            int m = M0 + wv * 16 + hi * 4 + r;
            pcontrib[m] = -0.5f * (LOGDET_C + quad[r]) - 0.5f * ls[r];
        }
    }
}

// ---------------------------------------------------------------------------
__global__ void k_fin(const f16* __restrict__ h1last,
                      const float* __restrict__ pcontrib, float* __restrict__ out)
{
    int gid = blockIdx.x * 256 + threadIdx.x;
    for (int i = gid; i < HSZ; i += 131072) out[i] = (float)h1last[i];
    if (gid < 512) {
        float s = 0.f;
        for (int tt = 0; tt < 128; tt++) s += pcontrib[tt * 512 + gid];
        out[HSZ + gid] = s;
    }
}

// ---------------------------------------------------------------------------
extern "C" void kernel_launch(void* const* d_in, const int* in_sizes, int n_in,
                              void* d_out, int out_size, void* d_ws, size_t ws_size,
                              hipStream_t stream) {
    const float* x     = (const float*)d_in[0];
    const float* mask  = (const float*)d_in[1];
    const float* Wih0  = (const float*)d_in[2];
    const float* Whh0  = (const float*)d_in[3];
    const float* b_ih0 = (const float*)d_in[4];
    const float* b_hh0 = (const float*)d_in[5];
    const float* Wih1  = (const float*)d_in[6];
    const float* Whh1  = (const float*)d_in[7];
    const float* b_ih1 = (const float*)d_in[8];
    const float* b_hh1 = (const float*)d_in[9];
    const float* W1    = (const float*)d_in[10];
    const float* b1    = (const float*)d_in[11];
    const float* W2    = (const float*)d_in[12];
    const float* b2    = (const float*)d_in[13];

    char* ws = (char*)d_ws;
    size_t off = 0;
    auto take = [&](size_t bytes) { char* p = ws + off; off += (bytes + 255) & ~(size_t)255; return p; };
    float* base    = (float*)take(512 * 512 * 4);
    f16* Whh0h     = (f16*)take(HSZ * 2);
    f16* Wih1h     = (f16*)take(HSZ * 2);
    f16* Whh1h     = (f16*)take(HSZ * 2);
    f16* W1h       = (f16*)take(1048576 * 2);
    f16* W2h       = (f16*)take(524288 * 2);
    f16* h0buf     = (f16*)take(2 * HSZ * 2);
    f16* h1all     = (f16*)take((size_t)129 * HSZ * 2);
    float* pcontrib= (float*)take(128 * 512 * 4);
    f16* A         = (f16*)take(65536 * 2);
    f16* B1        = (f16*)take(65536 * 2);
    float* biasv   = (float*)take(512 * 4);
    int* slots     = (int*)take(32768 * 4);
    int* xcdtab    = (int*)take(4096 * 4);
    if (off > ws_size) return;

    // Optional monotonic h0 slabs (66 MB): enables cached/virgin h0 reads.
    const size_t h0all_bytes = (size_t)129 * HSZ * 2;
    bool big = (off + h0all_bytes + 256 <= ws_size);
    f16* h0all = big ? (f16*)take(h0all_bytes) : h0buf;

    k_conv<<<256, 256, 0, stream>>>(x, mask, Wih0, b_ih0, b_hh0, Whh0, Wih1, Whh1,
                                    W1, W2, A, B1, biasv, Whh0h, Wih1h, Whh1h,
                                    W1h, W2h, h1all, slots, xcdtab);
    k_base<<<256, 256, 0, stream>>>(A, B1, biasv, base, h0all);
    if (big)
        k_rnn<true><<<256, 256, 0, stream>>>(h0all, h1all, Whh0h, Wih1h, Whh1h,
                                             base, x, Wih0, b_ih1, b_hh1, slots,
                                             xcdtab);
    else
        k_rnn<false><<<256, 256, 0, stream>>>(h0all, h1all, Whh0h, Wih1h, Whh1h,
                                              base, x, Wih0, b_ih1, b_hh1, slots,
                                              xcdtab);
    k_phaseB<<<512, 512, 0, stream>>>(h1all, W1h, W2h, b1, b2, x, pcontrib);
    k_fin<<<512, 256, 0, stream>>>(h1all + (size_t)128 * HSZ, pcontrib, (float*)d_out);
}